// Round 6
// baseline (1166.881 us; speedup 1.0000x reference)
//
#include <hip/hip_runtime.h>
#include <hip/hip_bf16.h>
#include <stdint.h>

#define BB 4
#define TT 2048
#define DD 1024
#define HH 16
#define MTOK (BB*TT)
#define NQ 4096            // q|k|v|g concat width
#define TC 32              // scan chunk length
#define NC (TT/TC)         // 64 chunks
#define BH (BB*HH)         // 64
#define ROWT (16*NQ)       // elements per 16-row blocked stripe

typedef __bf16 bf16x8 __attribute__((ext_vector_type(8)));
typedef float f32x16 __attribute__((ext_vector_type(16)));

__device__ __forceinline__ uint16_t f2bf(float f){
  uint32_t u = __float_as_uint(f);
  u += 0x7fffu + ((u >> 16) & 1u);
  return (uint16_t)(u >> 16);
}
__device__ __forceinline__ float bf2f(uint32_t h){ return __uint_as_float(h << 16); }
__device__ __forceinline__ float sigm(float z){ return 1.f / (1.f + __expf(-z)); }

__device__ __forceinline__ void gll16(const uint16_t* src, uint16_t* dst){
  __builtin_amdgcn_global_load_lds(
      (const __attribute__((address_space(1))) void*)src,
      (__attribute__((address_space(3))) void*)dst, 16, 0, 0);
}
// extract bf16 element e (static) from a uint4 (8 bf16)
__device__ __forceinline__ float bfel(const uint4& v, int e){
  uint32_t wrd = ((e>>1)==0) ? v.x : ((e>>1)==1) ? v.y : ((e>>1)==2) ? v.z : v.w;
  return bf2f((e&1) ? (wrd >> 16) : (wrd & 0xffffu));
}

// ---------------- fused weight f32 -> bf16 cast ----------------
__global__ __launch_bounds__(256) void wcvt_kernel(
    const float* __restrict__ w0, const float* __restrict__ w1,
    const float* __restrict__ w2, const float* __restrict__ w3,
    const float* __restrict__ w4, uint16_t* __restrict__ wcat, uint16_t* __restrict__ wob)
{
  int i = blockIdx.x * 256 + threadIdx.x;      // float4 index; 262144 per weight
  int wsel = i >> 18;
  int loc = i & 262143;
  const float* src = (wsel == 0) ? w0 : (wsel == 1) ? w1 : (wsel == 2) ? w2 : (wsel == 3) ? w3 : w4;
  uint16_t* dst = (wsel < 4) ? (wcat + (size_t)wsel * DD * DD) : wob;
  float4 v = ((const float4*)src)[loc];
  ushort4 o;
  o.x = f2bf(v.x); o.y = f2bf(v.y); o.z = f2bf(v.z); o.w = f2bf(v.w);
  ((ushort4*)dst)[loc] = o;
}

// =============== 128x128 GEMM, BK=64, m97 2-barrier structure, 32x32x16 MFMA ===============
// X:[M][K], W:[N][K] bf16 row-major. 256 thr = 4 waves (2x2), 64x64 per wave
// as 2x2 frags of 32x32. LDS 2x16KB, row stride 128B, per-8-row XOR swizzle on
// 16B chunks (R4-proven conflict-free): LDS chunk p holds logical
// (row=p>>3, quarter=(p&7)^(row&7)); inverse applied to global_load_lds source.
// Frag layout 32x32x16: A/B row|col = lane&31, k = (lane>>5)*8 + 0..7;
// C/D col=lane&31, row=(reg&3)+8*(reg>>2)+4*(lane>>5)  [m74/m101-verified].
// MODE 0: qkvg blocked bf16 out (silu cols<3072 else sigmoid); MODE 1: f32 row-major.
template<int MODE>
__global__ __launch_bounds__(256) void gemm128(
    const uint16_t* __restrict__ X, const uint16_t* __restrict__ W,
    uint16_t* __restrict__ Y, float* __restrict__ Yf, int N, int K)
{
  __shared__ __align__(16) uint16_t lA[128 * 64];
  __shared__ __align__(16) uint16_t lB[128 * 64];
  const int tid = threadIdx.x;
  const int m0 = blockIdx.y * 128, n0 = blockIdx.x * 128;
  const int l = tid & 63, w = tid >> 6;
  const int wr = w >> 1, wc = w & 1;
  const int lid = l & 31, hi = l >> 5;

  // staging (identical to R4): chunk p = n*256 + tid; row = p>>3, quarter = (p&7)^(row&7)
  const uint16_t* srcA[4];
  const uint16_t* srcB[4];
  uint16_t* dstA[4];
  uint16_t* dstB[4];
  #pragma unroll
  for (int n = 0; n < 4; n++){
    int p = n * 256 + tid;
    int row = p >> 3;
    int cq = (p & 7) ^ (row & 7);
    srcA[n] = X + (size_t)(m0 + row) * K + cq * 8;
    srcB[n] = W + (size_t)(n0 + row) * K + cq * 8;
    int basechunk = n * 256 + (tid & ~63);
    dstA[n] = lA + basechunk * 8;
    dstB[n] = lB + basechunk * 8;
  }

  // frag read offsets (u16): row*64 + ((kc*2+hi)^(row&7))*8, row = wseg + frag*32 + lid
  int roA[2][4], roB[2][4];
  #pragma unroll
  for (int fi = 0; fi < 2; fi++)
    #pragma unroll
    for (int kc = 0; kc < 4; kc++){
      roA[fi][kc] = (wr * 64 + fi * 32 + lid) * 64 + (((kc * 2 + hi) ^ (lid & 7)) * 8);
      roB[fi][kc] = (wc * 64 + fi * 32 + lid) * 64 + (((kc * 2 + hi) ^ (lid & 7)) * 8);
    }

  f32x16 acc[2][2];
  #pragma unroll
  for (int i = 0; i < 2; i++)
    #pragma unroll
    for (int j = 0; j < 2; j++)
      #pragma unroll
      for (int e = 0; e < 16; e++) acc[i][j][e] = 0.f;

  for (int kt = 0; kt < K; kt += 64){
    __syncthreads();                    // WAR: prior tile reads done
    #pragma unroll
    for (int n = 0; n < 4; n++){
      gll16(srcA[n] + kt, dstA[n]);
      gll16(srcB[n] + kt, dstB[n]);
    }
    __syncthreads();                    // drain -> LDS valid

    #pragma unroll
    for (int kc = 0; kc < 4; kc++){
      bf16x8 a0 = *(const bf16x8*)(lA + roA[0][kc]);
      bf16x8 a1 = *(const bf16x8*)(lA + roA[1][kc]);
      bf16x8 b0 = *(const bf16x8*)(lB + roB[0][kc]);
      bf16x8 b1 = *(const bf16x8*)(lB + roB[1][kc]);
      acc[0][0] = __builtin_amdgcn_mfma_f32_32x32x16_bf16(a0, b0, acc[0][0], 0, 0, 0);
      acc[0][1] = __builtin_amdgcn_mfma_f32_32x32x16_bf16(a0, b1, acc[0][1], 0, 0, 0);
      acc[1][0] = __builtin_amdgcn_mfma_f32_32x32x16_bf16(a1, b0, acc[1][0], 0, 0, 0);
      acc[1][1] = __builtin_amdgcn_mfma_f32_32x32x16_bf16(a1, b1, acc[1][1], 0, 0, 0);
    }
  }

  // epilogue
  if (MODE == 0){
    const bool dosig = (n0 >= 3 * DD);
    #pragma unroll
    for (int mi = 0; mi < 2; mi++){
      const int Rf = m0 + wr * 64 + mi * 32;
      #pragma unroll
      for (int ni = 0; ni < 2; ni++){
        const int C = n0 + wc * 64 + ni * 32 + lid;
        f32x16 v = acc[mi][ni];
        #pragma unroll
        for (int q4 = 0; q4 < 4; q4++){
          const int R = Rf + q4 * 8 + hi * 4;     // rows R..R+3
          float o[4];
          #pragma unroll
          for (int r = 0; r < 4; r++){
            float xx = v[q4 * 4 + r];
            o[r] = dosig ? sigm(xx) : xx * sigm(xx);
          }
          uint2 pk;
          pk.x = (uint32_t)f2bf(o[0]) | ((uint32_t)f2bf(o[1]) << 16);
          pk.y = (uint32_t)f2bf(o[2]) | ((uint32_t)f2bf(o[3]) << 16);
          size_t off = (size_t)(R >> 4) * ROWT + (size_t)(C >> 4) * 256 + (size_t)(C & 15) * 16 + (R & 15);
          *(uint2*)(Y + off) = pk;
        }
      }
    }
  } else {
    #pragma unroll
    for (int mi = 0; mi < 2; mi++){
      const int Rf = m0 + wr * 64 + mi * 32;
      #pragma unroll
      for (int ni = 0; ni < 2; ni++){
        const int C = n0 + wc * 64 + ni * 32 + lid;
        f32x16 v = acc[mi][ni];
        #pragma unroll
        for (int q4 = 0; q4 < 4; q4++){
          const int R = Rf + q4 * 8 + hi * 4;
          #pragma unroll
          for (int r = 0; r < 4; r++)
            Yf[(size_t)(R + r) * N + C] = v[q4 * 4 + r];
        }
      }
    }
  }
}

// ---------------- small projections fused with x->bf16 cast ----------------
__global__ __launch_bounds__(256) void small_proj_cast(
    const float* __restrict__ x,
    const float* __restrict__ Wb, const float* __restrict__ Wfd, const float* __restrict__ bfd,
    const float* __restrict__ Wsd, const float* __restrict__ bsd,
    float* __restrict__ sc, uint16_t* __restrict__ xb)
{
  int w = threadIdx.x >> 6, lane = threadIdx.x & 63;
  int tok0 = blockIdx.x * 16 + w * 4;

  float4 xv[4][4];
  #pragma unroll
  for (int tk = 0; tk < 4; tk++){
    const float4* xr = (const float4*)(x + (size_t)(tok0 + tk) * DD);
    #pragma unroll
    for (int i = 0; i < 4; i++) xv[tk][i] = xr[lane * 4 + i];
    uint4 o0, o1;
    o0.x = (uint32_t)f2bf(xv[tk][0].x) | ((uint32_t)f2bf(xv[tk][0].y) << 16);
    o0.y = (uint32_t)f2bf(xv[tk][0].z) | ((uint32_t)f2bf(xv[tk][0].w) << 16);
    o0.z = (uint32_t)f2bf(xv[tk][1].x) | ((uint32_t)f2bf(xv[tk][1].y) << 16);
    o0.w = (uint32_t)f2bf(xv[tk][1].z) | ((uint32_t)f2bf(xv[tk][1].w) << 16);
    o1.x = (uint32_t)f2bf(xv[tk][2].x) | ((uint32_t)f2bf(xv[tk][2].y) << 16);
    o1.y = (uint32_t)f2bf(xv[tk][2].z) | ((uint32_t)f2bf(xv[tk][2].w) << 16);
    o1.z = (uint32_t)f2bf(xv[tk][3].x) | ((uint32_t)f2bf(xv[tk][3].y) << 16);
    o1.w = (uint32_t)f2bf(xv[tk][3].z) | ((uint32_t)f2bf(xv[tk][3].w) << 16);
    uint4* xo = (uint4*)(xb + (size_t)(tok0 + tk) * DD + lane * 16);
    xo[0] = o0; xo[1] = o1;
  }

  for (int j = 0; j < 48; j++){
    int grp = j >> 4, h = j & 15;
    const float* wrow;
    float bias;
    if (grp == 0){ wrow = Wb  + (size_t)h * DD; bias = 0.f; }
    else if (grp == 1){ wrow = Wfd + (size_t)h * DD; bias = bfd[h]; }
    else { wrow = Wsd + (size_t)h * DD; bias = bsd[h]; }
    const float4* wr4 = (const float4*)wrow;
    float4 wv[4];
    #pragma unroll
    for (int i = 0; i < 4; i++) wv[i] = wr4[lane * 4 + i];
    #pragma unroll
    for (int tk = 0; tk < 4; tk++){
      float s = 0.f;
      #pragma unroll
      for (int i = 0; i < 4; i++)
        s += xv[tk][i].x * wv[i].x + xv[tk][i].y * wv[i].y + xv[tk][i].z * wv[i].z + xv[tk][i].w * wv[i].w;
      #pragma unroll
      for (int off = 32; off; off >>= 1) s += __shfl_xor(s, off);
      if (lane == 0){
        int token = tok0 + tk;
        int b = token / TT, t = token % TT;
        sc[(((size_t)grp * BB + b) * HH + h) * TT + t] = sigm(s + bias);
      }
    }
  }
}

// ---------------- fused chunked scan with decoupled lookback ----------------
// blocked elem(R,C) = (R>>4)*ROWT + (C>>4)*256 + (C&15)*16 + (R&15)
// step: [sf,ss]' = M_t [sf,ss] + 1.05*u_t*[1,1],  M_t = [[f,.05s],[.05f,s]]
// grid j-major: bid = j*BH + bh (predecessor (bh,j-1) has lower bid -> no deadlock)
// flags[bh*NC+j]: 0 = none, 1 = local (Lst,Pm) ready, 2 = inclusive (Ist) ready
__global__ __launch_bounds__(64) void scan_fused(
    const uint16_t* __restrict__ qkvg, const float* __restrict__ sc,
    float* __restrict__ Lst, float* __restrict__ Ist, float4* __restrict__ Pm,
    uint32_t* __restrict__ flags, uint16_t* __restrict__ og)
{
  __shared__ uint16_t ot[16 * 64];
  const int bid = blockIdx.x;
  const int j = bid / BH, bh = bid % BH;
  const int b = bh >> 4, h = bh & 15;
  const int c = threadIdx.x;
  const int ci = c & 15;
  const int idx = bh * NC + j;

  const size_t tc_q = (size_t)((         h * 64 + c) >> 4) * 256 + ci * 16;
  const size_t tc_k = (size_t)((DD     + h * 64 + c) >> 4) * 256 + ci * 16;
  const size_t tc_v = (size_t)((2 * DD + h * 64 + c) >> 4) * 256 + ci * 16;
  const size_t tc_g = (size_t)((3 * DD + h * 64 + c) >> 4) * 256 + ci * 16;
  const float* bet = sc + ((size_t)(0 * BB + b) * HH + h) * TT + j * TC;
  const float* fdp = sc + ((size_t)(1 * BB + b) * HH + h) * TT + j * TC;
  const float* sdp = sc + ((size_t)(2 * BB + b) * HH + h) * TT + j * TC;

  // ---- phase A: local scan (zero entry) + chunk 2x2 matrix ----
  float sfL = 0.f, ssL = 0.f;
  float p00 = 1.f, p01 = 0.f, p10 = 0.f, p11 = 1.f;
  #pragma unroll
  for (int t16 = 0; t16 < 2; ++t16){
    int R0 = b * TT + j * TC + t16 * 16;
    size_t tb = (size_t)(R0 >> 4) * ROWT;
    uint4 kl = *(const uint4*)(qkvg + tb + tc_k);
    uint4 kh = *(const uint4*)(qkvg + tb + tc_k + 8);
    uint4 vl = *(const uint4*)(qkvg + tb + tc_v);
    uint4 vh = *(const uint4*)(qkvg + tb + tc_v + 8);
    const float* bt = bet + t16 * 16;
    const float* ft = fdp + t16 * 16;
    const float* st = sdp + t16 * 16;
    #pragma unroll
    for (int u = 0; u < 16; ++u){
      float kv = (u < 8) ? bfel(kl, u) : bfel(kh, u - 8);
      float vv = (u < 8) ? bfel(vl, u) : bfel(vh, u - 8);
      float btv = bt[u], f = ft[u], s = st[u];
      float uu = 1.05f * btv * kv * vv;
      float bq = 0.05f * s, cq = 0.05f * f;
      float nf = f * sfL + bq * ssL + uu;
      float ns = cq * sfL + s * ssL + uu;
      sfL = nf; ssL = ns;
      float q00 = f * p00 + bq * p10, q01 = f * p01 + bq * p11;
      float q10 = cq * p00 + s * p10, q11 = cq * p01 + s * p11;
      p00 = q00; p01 = q01; p10 = q10; p11 = q11;
    }
  }
  {
    size_t base = (size_t)idx * 2;
    Lst[(base + 0) * 64 + c] = sfL;
    Lst[(base + 1) * 64 + c] = ssL;
    if (c == 0) Pm[idx] = make_float4(p00, p01, p10, p11);
    __threadfence();
    if (c == 0) atomicExch(&flags[idx], 1u);
  }

  // ---- lookback: entry state E = sum over i<j of Pacc * L_i (stop at inclusive) ----
  float ef = 0.f, es = 0.f;
  float pa = 1.f, pb = 0.f, pc = 0.f, pd = 1.f;
  for (int i = j - 1; i >= 0; --i){
    int pidx = bh * NC + i;
    int fl;
    if (c == 0){
      uint32_t fv;
      do { fv = atomicAdd(&flags[pidx], 0u); } while (fv == 0u);
      fl = (int)fv;
    }
    fl = __shfl(fl, 0);
    __threadfence();
    size_t pbase = (size_t)pidx * 2;
    if (fl >= 2){
      float inf = Ist[(pbase + 0) * 64 + c], ins = Ist[(pbase + 1) * 64 + c];
      ef += pa * inf + pb * ins;
      es += pc * inf + pd * ins;
      break;
    } else {
      float lf = Lst[(pbase + 0) * 64 + c], ls = Lst[(pbase + 1) * 64 + c];
      ef += pa * lf + pb * ls;
      es += pc * lf + pd * ls;
      float4 P = Pm[pidx];
      float na = pa * P.x + pb * P.z, nb = pa * P.y + pb * P.w;
      float nc2 = pc * P.x + pd * P.z, nd = pc * P.y + pd * P.w;
      pa = na; pb = nb; pc = nc2; pd = nd;
    }
  }

  // publish inclusive: I = P_local * E + L_local
  {
    size_t base = (size_t)idx * 2;
    Ist[(base + 0) * 64 + c] = p00 * ef + p01 * es + sfL;
    Ist[(base + 1) * 64 + c] = p10 * ef + p11 * es + ssL;
    __threadfence();
    if (c == 0) atomicExch(&flags[idx], 2u);
  }

  // ---- phase C: replay with entry state; write og row-major via LDS transpose ----
  float sf = ef, ss = es;
  #pragma unroll
  for (int t16 = 0; t16 < 2; ++t16){
    int R0 = b * TT + j * TC + t16 * 16;
    size_t tb = (size_t)(R0 >> 4) * ROWT;
    uint4 ql = *(const uint4*)(qkvg + tb + tc_q);
    uint4 qh = *(const uint4*)(qkvg + tb + tc_q + 8);
    uint4 kl = *(const uint4*)(qkvg + tb + tc_k);
    uint4 kh = *(const uint4*)(qkvg + tb + tc_k + 8);
    uint4 vl = *(const uint4*)(qkvg + tb + tc_v);
    uint4 vh = *(const uint4*)(qkvg + tb + tc_v + 8);
    uint4 gl = *(const uint4*)(qkvg + tb + tc_g);
    uint4 gh = *(const uint4*)(qkvg + tb + tc_g + 8);
    const float* bt = bet + t16 * 16;
    const float* ft = fdp + t16 * 16;
    const float* st = sdp + t16 * 16;
    #pragma unroll
    for (int u = 0; u < 16; ++u){
      float qv = (u < 8) ? bfel(ql, u) : bfel(qh, u - 8);
      float kv = (u < 8) ? bfel(kl, u) : bfel(kh, u - 8);
      float vv = (u < 8) ? bfel(vl, u) : bfel(vh, u - 8);
      float gv = (u < 8) ? bfel(gl, u) : bfel(gh, u - 8);
      float btv = bt[u], f = ft[u], s = st[u];
      sf *= f; ss *= s;
      float o = 0.5f * qv * (sf + ss);
      float uu = btv * kv * vv;
      sf += uu; ss += uu;
      float nf = sf + 0.05f * ss, ns = ss + 0.05f * sf;
      sf = nf; ss = ns;
      ot[u * 64 + c] = f2bf(o * gv);
    }
    __syncthreads();
    {
      int u0 = c >> 3, c8 = c & 7;
      uint4 d0 = *(const uint4*)&ot[u0 * 64 + c8 * 8];
      uint4 d1 = *(const uint4*)&ot[(u0 + 8) * 64 + c8 * 8];
      uint16_t* ob = og + (size_t)R0 * DD + h * 64 + c8 * 8;
      *(uint4*)(ob + (size_t)u0 * DD) = d0;
      *(uint4*)(ob + (size_t)(u0 + 8) * DD) = d1;
    }
    __syncthreads();
  }
}

extern "C" void kernel_launch(void* const* d_in, const int* in_sizes, int n_in,
                              void* d_out, int out_size, void* d_ws, size_t ws_size,
                              hipStream_t stream)
{
  const float* x   = (const float*)d_in[0];
  const float* Wq  = (const float*)d_in[1];
  const float* Wk  = (const float*)d_in[2];
  const float* Wv  = (const float*)d_in[3];
  const float* Wo  = (const float*)d_in[4];
  const float* Wb  = (const float*)d_in[5];
  const float* Wfd = (const float*)d_in[6];
  const float* bfd = (const float*)d_in[7];
  const float* Wsd = (const float*)d_in[8];
  const float* bsd = (const float*)d_in[9];
  const float* Wg  = (const float*)d_in[10];
  float* out = (float*)d_out;

  char* ws = (char*)d_ws;
  size_t off = 0;
  auto alloc = [&](size_t bytes) -> void* {
    void* p = ws + off;
    off += (bytes + 255) & ~(size_t)255;
    return p;
  };

  uint16_t* xb   = (uint16_t*)alloc((size_t)MTOK * DD * 2);   // doubles as ogb later
  uint16_t* wcat = (uint16_t*)alloc((size_t)4 * DD * DD * 2); // Wq|Wk|Wv|Wg
  uint16_t* wob  = (uint16_t*)alloc((size_t)DD * DD * 2);
  uint16_t* qkvg = (uint16_t*)alloc((size_t)MTOK * NQ * 2);   // blocked layout
  float*    sc   = (float*)alloc((size_t)3 * BB * HH * TT * 4);
  float*    Lst  = (float*)alloc((size_t)BH * NC * 2 * 64 * 4);
  float*    Ist  = (float*)alloc((size_t)BH * NC * 2 * 64 * 4);
  float4*   Pm   = (float4*)alloc((size_t)BH * NC * 16);
  uint32_t* flags= (uint32_t*)alloc((size_t)BH * NC * 4);
  uint16_t* ogb  = xb;

  // reset lookback flags (workspace is NOT re-poisoned between replays)
  hipMemsetAsync(flags, 0, (size_t)BH * NC * 4, stream);

  wcvt_kernel<<<5 * 1024, 256, 0, stream>>>(Wq, Wk, Wv, Wg, Wo, wcat, wob);

  small_proj_cast<<<MTOK / 16, 256, 0, stream>>>(x, Wb, Wfd, bfd, Wsd, bsd, sc, xb);

  // fused q|k|v|g GEMM: [8192,1024] @ [4096,1024]^T -> blocked bf16
  dim3 gq(NQ / 128, MTOK / 128);
  gemm128<0><<<gq, 256, 0, stream>>>(xb, wcat, qkvg, nullptr, NQ, DD);

  // fused chunked scan (A + lookback-combine + C)
  scan_fused<<<NC * BH, 64, 0, stream>>>(qkvg, sc, Lst, Ist, Pm, flags, ogb);

  // out = (o*g) @ Wo^T, fp32 row-major out
  dim3 go(DD / 128, MTOK / 128);
  gemm128<1><<<go, 256, 0, stream>>>(ogb, wob, nullptr, out, DD, DD);
}

// Round 7
// 241.968 us; speedup vs baseline: 4.8225x; 4.8225x over previous
//
#include <hip/hip_runtime.h>
#include <hip/hip_bf16.h>
#include <stdint.h>

#define BB 4
#define TT 2048
#define DD 1024
#define HH 16
#define MTOK (BB*TT)
#define NQ 4096            // q|k|v|g concat width
#define TC 32              // scan chunk length
#define NC (TT/TC)         // 64 chunks
#define BH (BB*HH)         // 64
#define ROWT (16*NQ)       // elements per 16-row blocked stripe

typedef __bf16 bf16x8 __attribute__((ext_vector_type(8)));
typedef float f32x4 __attribute__((ext_vector_type(4)));

__device__ __forceinline__ uint16_t f2bf(float f){
  uint32_t u = __float_as_uint(f);
  u += 0x7fffu + ((u >> 16) & 1u);
  return (uint16_t)(u >> 16);
}
__device__ __forceinline__ float bf2f(uint32_t h){ return __uint_as_float(h << 16); }
__device__ __forceinline__ float sigm(float z){ return 1.f / (1.f + __expf(-z)); }

__device__ __forceinline__ void gll16(const uint16_t* src, uint16_t* dst){
  __builtin_amdgcn_global_load_lds(
      (const __attribute__((address_space(1))) void*)src,
      (__attribute__((address_space(3))) void*)dst, 16, 0, 0);
}
// extract bf16 element e (static) from a uint4 (8 bf16)
__device__ __forceinline__ float bfel(const uint4& v, int e){
  uint32_t wrd = ((e>>1)==0) ? v.x : ((e>>1)==1) ? v.y : ((e>>1)==2) ? v.z : v.w;
  return bf2f((e&1) ? (wrd >> 16) : (wrd & 0xffffu));
}

// ---------------- fused weight f32 -> bf16 cast ----------------
__global__ __launch_bounds__(256) void wcvt_kernel(
    const float* __restrict__ w0, const float* __restrict__ w1,
    const float* __restrict__ w2, const float* __restrict__ w3,
    const float* __restrict__ w4, uint16_t* __restrict__ wcat, uint16_t* __restrict__ wob)
{
  int i = blockIdx.x * 256 + threadIdx.x;      // float4 index; 262144 per weight
  int wsel = i >> 18;
  int loc = i & 262143;
  const float* src = (wsel == 0) ? w0 : (wsel == 1) ? w1 : (wsel == 2) ? w2 : (wsel == 3) ? w3 : w4;
  uint16_t* dst = (wsel < 4) ? (wcat + (size_t)wsel * DD * DD) : wob;
  float4 v = ((const float4*)src)[loc];
  ushort4 o;
  o.x = f2bf(v.x); o.y = f2bf(v.y); o.z = f2bf(v.z); o.w = f2bf(v.w);
  ((ushort4*)dst)[loc] = o;
}

// =============== 128x128 GEMM, BK=64, double-buffered 2-phase (T3 minimum recipe) ===============
// X:[M][K], W:[N][K] bf16 row-major. 256 thr = 4 waves (2x2), 64x64 per wave.
// LDS 2 x (16KB A + 16KB B) = 64KB. Per K-tile: issue next-tile gll -> buf^1,
// ds_read+MFMA from buf[cur], then ONE vmcnt(0)+barrier (halves barriers vs R4;
// next-tile HBM latency hides under current tile's 32 MFMAs).
// Proven R4 swizzle: LDS chunk p holds logical (row=p>>3, quarter=(p&7)^(row&7));
// inverse applied to global source of global_load_lds (rule #21) -> 0 conflicts.
// MODE 0: qkvg blocked bf16 out (silu cols<3072 else sigmoid); MODE 1: f32 row-major.
template<int MODE>
__global__ __launch_bounds__(256) void gemm128(
    const uint16_t* __restrict__ X, const uint16_t* __restrict__ W,
    uint16_t* __restrict__ Y, float* __restrict__ Yf, int N, int K)
{
  constexpr int BUF = 128 * 64;                 // u16 per buffer
  __shared__ __align__(16) uint16_t lA[2 * BUF];
  __shared__ __align__(16) uint16_t lB[2 * BUF];
  const int tid = threadIdx.x;
  const int m0 = blockIdx.y * 128, n0 = blockIdx.x * 128;
  const int l = tid & 63, w = tid >> 6;
  const int wr = w >> 1, wc = w & 1;
  const int g = l >> 4, r16 = l & 15;

  // staging: chunk p = n*256 + tid; row = p>>3, logical quarter = (p&7)^(row&7)
  const uint16_t* srcA[4];
  const uint16_t* srcB[4];
  int dstOff[4];                                // u16 offset within a buffer (wave-uniform)
  #pragma unroll
  for (int n = 0; n < 4; n++){
    int p = n * 256 + tid;
    int row = p >> 3;
    int cq = (p & 7) ^ (row & 7);
    srcA[n] = X + (size_t)(m0 + row) * K + cq * 8;
    srcB[n] = W + (size_t)(n0 + row) * K + cq * 8;
    dstOff[n] = (n * 256 + (tid & ~63)) * 8;
  }

  // frag read offsets (u16 idx): row*64 + ((ks*4+g)^(row&7))*8
  int roA[4][2], roB[4][2];
  #pragma unroll
  for (int i = 0; i < 4; i++)
    #pragma unroll
    for (int ks = 0; ks < 2; ks++){
      roA[i][ks] = (wr * 64 + i * 16 + r16) * 64 + ((ks * 4 + g) ^ (r16 & 7)) * 8;
      roB[i][ks] = (wc * 64 + i * 16 + r16) * 64 + ((ks * 4 + g) ^ (r16 & 7)) * 8;
    }

  f32x4 acc[4][4];
  #pragma unroll
  for (int i = 0; i < 4; i++)
    #pragma unroll
    for (int j = 0; j < 4; j++) acc[i][j] = (f32x4){0.f, 0.f, 0.f, 0.f};

  // prologue: stage tile 0 -> buf 0
  #pragma unroll
  for (int n = 0; n < 4; n++){
    gll16(srcA[n], lA + dstOff[n]);
    gll16(srcB[n], lB + dstOff[n]);
  }
  asm volatile("s_waitcnt vmcnt(0)" ::: "memory");
  __builtin_amdgcn_sched_barrier(0);
  __builtin_amdgcn_s_barrier();

  int cur = 0;
  #pragma unroll 1
  for (int kt = 0; kt < K; kt += 64){
    const bool haveNext = (kt + 64 < K);
    // issue next-tile loads into buf^1 (its last readers finished before the
    // barrier that ended the previous iteration)
    if (haveNext){
      const int nb = (cur ^ 1) * BUF;
      #pragma unroll
      for (int n = 0; n < 4; n++){
        gll16(srcA[n] + kt + 64, lA + nb + dstOff[n]);
        gll16(srcB[n] + kt + 64, lB + nb + dstOff[n]);
      }
    }

    const uint16_t* rA = lA + cur * BUF;
    const uint16_t* rB = lB + cur * BUF;
    #pragma unroll
    for (int ks = 0; ks < 2; ks++){
      bf16x8 af[4], bw[4];
      #pragma unroll
      for (int mi = 0; mi < 4; mi++) af[mi] = *(const bf16x8*)(rA + roA[mi][ks]);
      #pragma unroll
      for (int ni = 0; ni < 4; ni++) bw[ni] = *(const bf16x8*)(rB + roB[ni][ks]);
      #pragma unroll
      for (int mi = 0; mi < 4; mi++)
        #pragma unroll
        for (int ni = 0; ni < 4; ni++)
          acc[mi][ni] = __builtin_amdgcn_mfma_f32_16x16x32_bf16(af[mi], bw[ni], acc[mi][ni], 0, 0, 0);
    }

    if (haveNext){
      asm volatile("s_waitcnt vmcnt(0)" ::: "memory");   // next tile resident
      __builtin_amdgcn_sched_barrier(0);
      __builtin_amdgcn_s_barrier();                      // all waves' reads of buf^1 done
    }
    cur ^= 1;
  }

  // C/D layout: col=lane&15, row=(lane>>4)*4+reg  [m89-verified]
  if (MODE == 0){
    const bool dosig = (n0 >= 3 * DD);
    #pragma unroll
    for (int mi = 0; mi < 4; mi++){
      const int R0 = m0 + wr * 64 + mi * 16;
      const size_t rbase = (size_t)(R0 >> 4) * ROWT;
      #pragma unroll
      for (int ni = 0; ni < 4; ni++){
        const int C0 = n0 + wc * 64 + ni * 16;
        f32x4 v = acc[mi][ni];
        float o[4];
        #pragma unroll
        for (int r = 0; r < 4; r++){
          float xx = v[r];
          o[r] = dosig ? sigm(xx) : xx * sigm(xx);
        }
        uint2 pk;
        pk.x = (uint32_t)f2bf(o[0]) | ((uint32_t)f2bf(o[1]) << 16);
        pk.y = (uint32_t)f2bf(o[2]) | ((uint32_t)f2bf(o[3]) << 16);
        size_t off = rbase + (size_t)(C0 >> 4) * 256 + (size_t)r16 * 16 + g * 4;
        *(uint2*)(Y + off) = pk;
      }
    }
  } else {
    #pragma unroll
    for (int mi = 0; mi < 4; mi++){
      #pragma unroll
      for (int ni = 0; ni < 4; ni++){
        int rg = m0 + wr * 64 + mi * 16 + g * 4;
        int cg = n0 + wc * 64 + ni * 16 + r16;
        #pragma unroll
        for (int r = 0; r < 4; r++)
          Yf[(size_t)(rg + r) * N + cg] = acc[mi][ni][r];
      }
    }
  }
}

// ---------------- small projections fused with x->bf16 cast ----------------
__global__ __launch_bounds__(256) void small_proj_cast(
    const float* __restrict__ x,
    const float* __restrict__ Wb, const float* __restrict__ Wfd, const float* __restrict__ bfd,
    const float* __restrict__ Wsd, const float* __restrict__ bsd,
    float* __restrict__ sc, uint16_t* __restrict__ xb)
{
  int w = threadIdx.x >> 6, lane = threadIdx.x & 63;
  int tok0 = blockIdx.x * 16 + w * 4;

  float4 xv[4][4];
  #pragma unroll
  for (int tk = 0; tk < 4; tk++){
    const float4* xr = (const float4*)(x + (size_t)(tok0 + tk) * DD);
    #pragma unroll
    for (int i = 0; i < 4; i++) xv[tk][i] = xr[lane * 4 + i];
    uint4 o0, o1;
    o0.x = (uint32_t)f2bf(xv[tk][0].x) | ((uint32_t)f2bf(xv[tk][0].y) << 16);
    o0.y = (uint32_t)f2bf(xv[tk][0].z) | ((uint32_t)f2bf(xv[tk][0].w) << 16);
    o0.z = (uint32_t)f2bf(xv[tk][1].x) | ((uint32_t)f2bf(xv[tk][1].y) << 16);
    o0.w = (uint32_t)f2bf(xv[tk][1].z) | ((uint32_t)f2bf(xv[tk][1].w) << 16);
    o1.x = (uint32_t)f2bf(xv[tk][2].x) | ((uint32_t)f2bf(xv[tk][2].y) << 16);
    o1.y = (uint32_t)f2bf(xv[tk][2].z) | ((uint32_t)f2bf(xv[tk][2].w) << 16);
    o1.z = (uint32_t)f2bf(xv[tk][3].x) | ((uint32_t)f2bf(xv[tk][3].y) << 16);
    o1.w = (uint32_t)f2bf(xv[tk][3].z) | ((uint32_t)f2bf(xv[tk][3].w) << 16);
    uint4* xo = (uint4*)(xb + (size_t)(tok0 + tk) * DD + lane * 16);
    xo[0] = o0; xo[1] = o1;
  }

  for (int j = 0; j < 48; j++){
    int grp = j >> 4, h = j & 15;
    const float* wrow;
    float bias;
    if (grp == 0){ wrow = Wb  + (size_t)h * DD; bias = 0.f; }
    else if (grp == 1){ wrow = Wfd + (size_t)h * DD; bias = bfd[h]; }
    else { wrow = Wsd + (size_t)h * DD; bias = bsd[h]; }
    const float4* wr4 = (const float4*)wrow;
    float4 wv[4];
    #pragma unroll
    for (int i = 0; i < 4; i++) wv[i] = wr4[lane * 4 + i];
    #pragma unroll
    for (int tk = 0; tk < 4; tk++){
      float s = 0.f;
      #pragma unroll
      for (int i = 0; i < 4; i++)
        s += xv[tk][i].x * wv[i].x + xv[tk][i].y * wv[i].y + xv[tk][i].z * wv[i].z + xv[tk][i].w * wv[i].w;
      #pragma unroll
      for (int off = 32; off; off >>= 1) s += __shfl_xor(s, off);
      if (lane == 0){
        int token = tok0 + tk;
        int b = token / TT, t = token % TT;
        sc[(((size_t)grp * BB + b) * HH + h) * TT + t] = sigm(s + bias);
      }
    }
  }
}

// ---------------- chunked scan over blocked qkvg (R4-proven 3-kernel version) ----------------
// blocked elem(R,C) = (R>>4)*ROWT + (C>>4)*256 + (C&15)*16 + (R&15)
// step: [sf,ss]' = M_t [sf,ss] + 1.05*u_t*[1,1],  M_t = [[f,.05s],[.05f,s]]

__global__ __launch_bounds__(64) void scan_partA(
    const uint16_t* __restrict__ qkvg, const float* __restrict__ sc,
    float* __restrict__ Lst, float4* __restrict__ Pm)
{
  int j = blockIdx.x, bh = blockIdx.y;
  int b = bh >> 4, h = bh & 15;
  int c = threadIdx.x;
  const int ci = c & 15;
  const size_t tc_k = (size_t)((DD     + h * 64 + c) >> 4) * 256 + ci * 16;
  const size_t tc_v = (size_t)((2 * DD + h * 64 + c) >> 4) * 256 + ci * 16;
  const float* bet = sc + ((size_t)(0 * BB + b) * HH + h) * TT + j * TC;
  const float* fdp = sc + ((size_t)(1 * BB + b) * HH + h) * TT + j * TC;
  const float* sdp = sc + ((size_t)(2 * BB + b) * HH + h) * TT + j * TC;

  float sf = 0.f, ss = 0.f;
  float p00 = 1.f, p01 = 0.f, p10 = 0.f, p11 = 1.f;
  #pragma unroll
  for (int t16 = 0; t16 < 2; ++t16){
    int R0 = b * TT + j * TC + t16 * 16;
    size_t tb = (size_t)(R0 >> 4) * ROWT;
    uint4 kl = *(const uint4*)(qkvg + tb + tc_k);
    uint4 kh = *(const uint4*)(qkvg + tb + tc_k + 8);
    uint4 vl = *(const uint4*)(qkvg + tb + tc_v);
    uint4 vh = *(const uint4*)(qkvg + tb + tc_v + 8);
    const float* bt = bet + t16 * 16;
    const float* ft = fdp + t16 * 16;
    const float* st = sdp + t16 * 16;
    #pragma unroll
    for (int u = 0; u < 16; ++u){
      float kv = (u < 8) ? bfel(kl, u) : bfel(kh, u - 8);
      float vv = (u < 8) ? bfel(vl, u) : bfel(vh, u - 8);
      float btv = bt[u], f = ft[u], s = st[u];
      float uu = 1.05f * btv * kv * vv;
      float bq = 0.05f * s, cq = 0.05f * f;
      float nf = f * sf + bq * ss + uu;
      float ns = cq * sf + s * ss + uu;
      sf = nf; ss = ns;
      float q00 = f * p00 + bq * p10, q01 = f * p01 + bq * p11;
      float q10 = cq * p00 + s * p10, q11 = cq * p01 + s * p11;
      p00 = q00; p01 = q01; p10 = q10; p11 = q11;
    }
  }
  size_t base = ((size_t)bh * NC + j) * 2;
  Lst[(base + 0) * 64 + c] = sf;
  Lst[(base + 1) * 64 + c] = ss;
  if (c == 0) Pm[(size_t)bh * NC + j] = make_float4(p00, p01, p10, p11);
}

__global__ __launch_bounds__(64) void scan_partB(
    const float* __restrict__ Lst, const float4* __restrict__ Pm, float* __restrict__ Est)
{
  int bh = blockIdx.x, dc = threadIdx.x;
  float xf = 0.f, xs = 0.f;
  for (int j = 0; j < NC; j++){
    size_t base = ((size_t)bh * NC + j) * 2;
    Est[(base + 0) * 64 + dc] = xf;
    Est[(base + 1) * 64 + dc] = xs;
    float4 P = Pm[(size_t)bh * NC + j];
    float lf = Lst[(base + 0) * 64 + dc], ls = Lst[(base + 1) * 64 + dc];
    float nf = P.x * xf + P.y * xs + lf;
    float ns = P.z * xf + P.w * xs + ls;
    xf = nf; xs = ns;
  }
}

__global__ __launch_bounds__(64) void scan_partC(
    const uint16_t* __restrict__ qkvg, const float* __restrict__ sc,
    const float* __restrict__ Est, uint16_t* __restrict__ og)
{
  __shared__ uint16_t ot[16 * 64];
  int j = blockIdx.x, bh = blockIdx.y;
  int b = bh >> 4, h = bh & 15;
  int c = threadIdx.x;
  const int ci = c & 15;
  const size_t tc_q = (size_t)((         h * 64 + c) >> 4) * 256 + ci * 16;
  const size_t tc_k = (size_t)((DD     + h * 64 + c) >> 4) * 256 + ci * 16;
  const size_t tc_v = (size_t)((2 * DD + h * 64 + c) >> 4) * 256 + ci * 16;
  const size_t tc_g = (size_t)((3 * DD + h * 64 + c) >> 4) * 256 + ci * 16;
  const float* bet = sc + ((size_t)(0 * BB + b) * HH + h) * TT + j * TC;
  const float* fdp = sc + ((size_t)(1 * BB + b) * HH + h) * TT + j * TC;
  const float* sdp = sc + ((size_t)(2 * BB + b) * HH + h) * TT + j * TC;

  size_t base = ((size_t)bh * NC + j) * 2;
  float sf = Est[(base + 0) * 64 + c];
  float ss = Est[(base + 1) * 64 + c];

  #pragma unroll
  for (int t16 = 0; t16 < 2; ++t16){
    int R0 = b * TT + j * TC + t16 * 16;
    size_t tb = (size_t)(R0 >> 4) * ROWT;
    uint4 ql = *(const uint4*)(qkvg + tb + tc_q);
    uint4 qh = *(const uint4*)(qkvg + tb + tc_q + 8);
    uint4 kl = *(const uint4*)(qkvg + tb + tc_k);
    uint4 kh = *(const uint4*)(qkvg + tb + tc_k + 8);
    uint4 vl = *(const uint4*)(qkvg + tb + tc_v);
    uint4 vh = *(const uint4*)(qkvg + tb + tc_v + 8);
    uint4 gl = *(const uint4*)(qkvg + tb + tc_g);
    uint4 gh = *(const uint4*)(qkvg + tb + tc_g + 8);
    const float* bt = bet + t16 * 16;
    const float* ft = fdp + t16 * 16;
    const float* st = sdp + t16 * 16;
    #pragma unroll
    for (int u = 0; u < 16; ++u){
      float qv = (u < 8) ? bfel(ql, u) : bfel(qh, u - 8);
      float kv = (u < 8) ? bfel(kl, u) : bfel(kh, u - 8);
      float vv = (u < 8) ? bfel(vl, u) : bfel(vh, u - 8);
      float gv = (u < 8) ? bfel(gl, u) : bfel(gh, u - 8);
      float btv = bt[u], f = ft[u], s = st[u];
      sf *= f; ss *= s;
      float o = 0.5f * qv * (sf + ss);
      float uu = btv * kv * vv;
      sf += uu; ss += uu;
      float nf = sf + 0.05f * ss, ns = ss + 0.05f * sf;
      sf = nf; ss = ns;
      ot[u * 64 + c] = f2bf(o * gv);
    }
    __syncthreads();
    {
      int u0 = c >> 3, c8 = c & 7;
      uint4 d0 = *(const uint4*)&ot[u0 * 64 + c8 * 8];
      uint4 d1 = *(const uint4*)&ot[(u0 + 8) * 64 + c8 * 8];
      uint16_t* ob = og + (size_t)R0 * DD + h * 64 + c8 * 8;
      *(uint4*)(ob + (size_t)u0 * DD) = d0;
      *(uint4*)(ob + (size_t)(u0 + 8) * DD) = d1;
    }
    __syncthreads();
  }
}

extern "C" void kernel_launch(void* const* d_in, const int* in_sizes, int n_in,
                              void* d_out, int out_size, void* d_ws, size_t ws_size,
                              hipStream_t stream)
{
  const float* x   = (const float*)d_in[0];
  const float* Wq  = (const float*)d_in[1];
  const float* Wk  = (const float*)d_in[2];
  const float* Wv  = (const float*)d_in[3];
  const float* Wo  = (const float*)d_in[4];
  const float* Wb  = (const float*)d_in[5];
  const float* Wfd = (const float*)d_in[6];
  const float* bfd = (const float*)d_in[7];
  const float* Wsd = (const float*)d_in[8];
  const float* bsd = (const float*)d_in[9];
  const float* Wg  = (const float*)d_in[10];
  float* out = (float*)d_out;

  char* ws = (char*)d_ws;
  size_t off = 0;
  auto alloc = [&](size_t bytes) -> void* {
    void* p = ws + off;
    off += (bytes + 255) & ~(size_t)255;
    return p;
  };

  uint16_t* xb   = (uint16_t*)alloc((size_t)MTOK * DD * 2);   // doubles as ogb later
  uint16_t* wcat = (uint16_t*)alloc((size_t)4 * DD * DD * 2); // Wq|Wk|Wv|Wg
  uint16_t* wob  = (uint16_t*)alloc((size_t)DD * DD * 2);
  uint16_t* qkvg = (uint16_t*)alloc((size_t)MTOK * NQ * 2);   // blocked layout
  float*    sc   = (float*)alloc((size_t)3 * BB * HH * TT * 4);
  float*    Lst  = (float*)alloc((size_t)BH * NC * 2 * 64 * 4);
  float*    Est  = (float*)alloc((size_t)BH * NC * 2 * 64 * 4);
  float4*   Pm   = (float4*)alloc((size_t)BH * NC * 16);
  uint16_t* ogb  = xb;

  wcvt_kernel<<<5 * 1024, 256, 0, stream>>>(Wq, Wk, Wv, Wg, Wo, wcat, wob);

  small_proj_cast<<<MTOK / 16, 256, 0, stream>>>(x, Wb, Wfd, bfd, Wsd, bsd, sc, xb);

  // fused q|k|v|g GEMM: [8192,1024] @ [4096,1024]^T -> blocked bf16
  dim3 gq(NQ / 128, MTOK / 128);
  gemm128<0><<<gq, 256, 0, stream>>>(xb, wcat, qkvg, nullptr, NQ, DD);

  // chunked scan (R4-proven 3-kernel version)
  dim3 gs(NC, BH);
  scan_partA<<<gs, 64, 0, stream>>>(qkvg, sc, Lst, Pm);
  scan_partB<<<BH, 64, 0, stream>>>(Lst, Pm, Est);
  scan_partC<<<gs, 64, 0, stream>>>(qkvg, sc, Est, ogb);

  // out = (o*g) @ Wo^T, fp32 row-major out
  dim3 go(DD / 128, MTOK / 128);
  gemm128<1><<<go, 256, 0, stream>>>(ogb, wob, nullptr, out, DD, DD);
}

// Round 8
// 222.074 us; speedup vs baseline: 5.2545x; 1.0896x over previous
//
#include <hip/hip_runtime.h>
#include <hip/hip_bf16.h>
#include <stdint.h>

#define BB 4
#define TT 2048
#define DD 1024
#define HH 16
#define MTOK (BB*TT)
#define NQ 4096            // q|k|v|g concat width
#define TC 32              // scan chunk length
#define NC (TT/TC)         // 64 chunks
#define BH (BB*HH)         // 64
#define ROWT (16*NQ)       // elements per 16-row blocked stripe

typedef __bf16 bf16x8 __attribute__((ext_vector_type(8)));
typedef float f32x4 __attribute__((ext_vector_type(4)));

__device__ __forceinline__ uint16_t f2bf(float f){
  uint32_t u = __float_as_uint(f);
  u += 0x7fffu + ((u >> 16) & 1u);
  return (uint16_t)(u >> 16);
}
__device__ __forceinline__ float bf2f(uint32_t h){ return __uint_as_float(h << 16); }
// sigmoid via fast exp + raw v_rcp_f32 (1 ulp) -- avoids precise-div expansion
__device__ __forceinline__ float sigm(float z){
  return __builtin_amdgcn_rcpf(1.f + __expf(-z));
}

__device__ __forceinline__ void gll16(const uint16_t* src, uint16_t* dst){
  __builtin_amdgcn_global_load_lds(
      (const __attribute__((address_space(1))) void*)src,
      (__attribute__((address_space(3))) void*)dst, 16, 0, 0);
}
// extract bf16 element e (static) from a uint4 (8 bf16)
__device__ __forceinline__ float bfel(const uint4& v, int e){
  uint32_t wrd = ((e>>1)==0) ? v.x : ((e>>1)==1) ? v.y : ((e>>1)==2) ? v.z : v.w;
  return bf2f((e&1) ? (wrd >> 16) : (wrd & 0xffffu));
}

// ---------------- prep: fused weight-cast (blocks 0..5119) + small-proj+x-cast (5120..5631) ----------------
__global__ __launch_bounds__(256) void prep_kernel(
    const float* __restrict__ x,
    const float* __restrict__ Wq, const float* __restrict__ Wk,
    const float* __restrict__ Wv, const float* __restrict__ Wg,
    const float* __restrict__ Wo,
    const float* __restrict__ Wb, const float* __restrict__ Wfd, const float* __restrict__ bfd,
    const float* __restrict__ Wsd, const float* __restrict__ bsd,
    uint16_t* __restrict__ wcat, uint16_t* __restrict__ wob,
    float* __restrict__ sc, uint16_t* __restrict__ xb)
{
  if (blockIdx.x < 5120){
    // weight f32 -> bf16 cast: Wq|Wk|Wv|Wg -> wcat, Wo -> wob
    int i = blockIdx.x * 256 + threadIdx.x;      // float4 index; 262144 per weight
    int wsel = i >> 18;
    int loc = i & 262143;
    const float* src = (wsel == 0) ? Wq : (wsel == 1) ? Wk : (wsel == 2) ? Wv : (wsel == 3) ? Wg : Wo;
    uint16_t* dst = (wsel < 4) ? (wcat + (size_t)wsel * DD * DD) : wob;
    float4 v = ((const float4*)src)[loc];
    ushort4 o;
    o.x = f2bf(v.x); o.y = f2bf(v.y); o.z = f2bf(v.z); o.w = f2bf(v.w);
    ((ushort4*)dst)[loc] = o;
    return;
  }

  // small projections + x cast; 16 tokens per block (4 per wave)
  int blk = blockIdx.x - 5120;
  int w = threadIdx.x >> 6, lane = threadIdx.x & 63;
  int tok0 = blk * 16 + w * 4;

  float4 xv[4][4];
  #pragma unroll
  for (int tk = 0; tk < 4; tk++){
    const float4* xr = (const float4*)(x + (size_t)(tok0 + tk) * DD);
    #pragma unroll
    for (int i = 0; i < 4; i++) xv[tk][i] = xr[lane * 4 + i];
    uint4 o0, o1;
    o0.x = (uint32_t)f2bf(xv[tk][0].x) | ((uint32_t)f2bf(xv[tk][0].y) << 16);
    o0.y = (uint32_t)f2bf(xv[tk][0].z) | ((uint32_t)f2bf(xv[tk][0].w) << 16);
    o0.z = (uint32_t)f2bf(xv[tk][1].x) | ((uint32_t)f2bf(xv[tk][1].y) << 16);
    o0.w = (uint32_t)f2bf(xv[tk][1].z) | ((uint32_t)f2bf(xv[tk][1].w) << 16);
    o1.x = (uint32_t)f2bf(xv[tk][2].x) | ((uint32_t)f2bf(xv[tk][2].y) << 16);
    o1.y = (uint32_t)f2bf(xv[tk][2].z) | ((uint32_t)f2bf(xv[tk][2].w) << 16);
    o1.z = (uint32_t)f2bf(xv[tk][3].x) | ((uint32_t)f2bf(xv[tk][3].y) << 16);
    o1.w = (uint32_t)f2bf(xv[tk][3].z) | ((uint32_t)f2bf(xv[tk][3].w) << 16);
    uint4* xo = (uint4*)(xb + (size_t)(tok0 + tk) * DD + lane * 16);
    xo[0] = o0; xo[1] = o1;
  }

  for (int j = 0; j < 48; j++){
    int grp = j >> 4, h = j & 15;
    const float* wrow;
    float bias;
    if (grp == 0){ wrow = Wb  + (size_t)h * DD; bias = 0.f; }
    else if (grp == 1){ wrow = Wfd + (size_t)h * DD; bias = bfd[h]; }
    else { wrow = Wsd + (size_t)h * DD; bias = bsd[h]; }
    const float4* wr4 = (const float4*)wrow;
    float4 wv[4];
    #pragma unroll
    for (int i = 0; i < 4; i++) wv[i] = wr4[lane * 4 + i];
    #pragma unroll
    for (int tk = 0; tk < 4; tk++){
      float s = 0.f;
      #pragma unroll
      for (int i = 0; i < 4; i++)
        s += xv[tk][i].x * wv[i].x + xv[tk][i].y * wv[i].y + xv[tk][i].z * wv[i].z + xv[tk][i].w * wv[i].w;
      #pragma unroll
      for (int off = 32; off; off >>= 1) s += __shfl_xor(s, off);
      if (lane == 0){
        int token = tok0 + tk;
        int b = token / TT, t = token % TT;
        sc[(((size_t)grp * BB + b) * HH + h) * TT + t] = sigm(s + bias);
      }
    }
  }
}

// =============== 128x128 GEMM, BK=64, m97 2-barrier structure (R4-proven) ===============
// X:[M][K], W:[N][K] bf16 row-major. 256 thr = 4 waves (2x2), 64x64 per wave.
// LDS 2x16KB single-buffered. Per-8-row XOR swizzle on 16B chunks:
// LDS chunk p holds logical (row=p>>3, quarter=(p&7)^(row&7)); inverse applied
// to the global source of global_load_lds (rule #21) -> 0 bank conflicts (R4 PMC).
// MODE 0: qkvg blocked bf16 out (silu cols<3072 else sigmoid); MODE 1: f32 row-major.
template<int MODE>
__global__ __launch_bounds__(256) void gemm128(
    const uint16_t* __restrict__ X, const uint16_t* __restrict__ W,
    uint16_t* __restrict__ Y, float* __restrict__ Yf, int N, int K)
{
  __shared__ __align__(16) uint16_t lA[128 * 64];
  __shared__ __align__(16) uint16_t lB[128 * 64];
  const int tid = threadIdx.x;
  const int m0 = blockIdx.y * 128, n0 = blockIdx.x * 128;
  const int l = tid & 63, w = tid >> 6;
  const int wr = w >> 1, wc = w & 1;
  const int g = l >> 4, r16 = l & 15;

  // staging: chunk p = n*256 + tid; row = p>>3, logical quarter = (p&7)^(row&7)
  const uint16_t* srcA[4];
  const uint16_t* srcB[4];
  uint16_t* dstA[4];
  uint16_t* dstB[4];
  #pragma unroll
  for (int n = 0; n < 4; n++){
    int p = n * 256 + tid;
    int row = p >> 3;
    int cq = (p & 7) ^ (row & 7);
    srcA[n] = X + (size_t)(m0 + row) * K + cq * 8;
    srcB[n] = W + (size_t)(n0 + row) * K + cq * 8;
    int basechunk = n * 256 + (tid & ~63);     // wave-uniform
    dstA[n] = lA + basechunk * 8;
    dstB[n] = lB + basechunk * 8;
  }

  // frag read offsets (u16 idx): row*64 + ((ks*4+g)^(row&7))*8
  int roA[4][2], roB[4][2];
  #pragma unroll
  for (int i = 0; i < 4; i++)
    #pragma unroll
    for (int ks = 0; ks < 2; ks++){
      roA[i][ks] = (wr * 64 + i * 16 + r16) * 64 + ((ks * 4 + g) ^ (r16 & 7)) * 8;
      roB[i][ks] = (wc * 64 + i * 16 + r16) * 64 + ((ks * 4 + g) ^ (r16 & 7)) * 8;
    }

  f32x4 acc[4][4];
  #pragma unroll
  for (int i = 0; i < 4; i++)
    #pragma unroll
    for (int j = 0; j < 4; j++) acc[i][j] = (f32x4){0.f, 0.f, 0.f, 0.f};

  for (int kt = 0; kt < K; kt += 64){
    __syncthreads();                    // WAR: prior tile reads done
    #pragma unroll
    for (int n = 0; n < 4; n++){
      gll16(srcA[n] + kt, dstA[n]);
      gll16(srcB[n] + kt, dstB[n]);
    }
    __syncthreads();                    // compiler drains vmcnt(0) before barrier

    #pragma unroll
    for (int ks = 0; ks < 2; ks++){
      bf16x8 af[4], bw[4];
      #pragma unroll
      for (int mi = 0; mi < 4; mi++) af[mi] = *(const bf16x8*)(lA + roA[mi][ks]);
      #pragma unroll
      for (int ni = 0; ni < 4; ni++) bw[ni] = *(const bf16x8*)(lB + roB[ni][ks]);
      #pragma unroll
      for (int mi = 0; mi < 4; mi++)
        #pragma unroll
        for (int ni = 0; ni < 4; ni++)
          acc[mi][ni] = __builtin_amdgcn_mfma_f32_16x16x32_bf16(af[mi], bw[ni], acc[mi][ni], 0, 0, 0);
    }
  }

  // C/D layout: col=lane&15, row=(lane>>4)*4+reg  [m89-verified]
  if (MODE == 0){
    const bool dosig = (n0 >= 3 * DD);
    #pragma unroll
    for (int mi = 0; mi < 4; mi++){
      const int R0 = m0 + wr * 64 + mi * 16;
      const size_t rbase = (size_t)(R0 >> 4) * ROWT;
      #pragma unroll
      for (int ni = 0; ni < 4; ni++){
        const int C0 = n0 + wc * 64 + ni * 16;
        f32x4 v = acc[mi][ni];
        float o[4];
        #pragma unroll
        for (int r = 0; r < 4; r++){
          float xx = v[r];
          o[r] = dosig ? sigm(xx) : xx * sigm(xx);
        }
        uint2 pk;
        pk.x = (uint32_t)f2bf(o[0]) | ((uint32_t)f2bf(o[1]) << 16);
        pk.y = (uint32_t)f2bf(o[2]) | ((uint32_t)f2bf(o[3]) << 16);
        size_t off = rbase + (size_t)(C0 >> 4) * 256 + (size_t)r16 * 16 + g * 4;
        *(uint2*)(Y + off) = pk;
      }
    }
  } else {
    #pragma unroll
    for (int mi = 0; mi < 4; mi++){
      #pragma unroll
      for (int ni = 0; ni < 4; ni++){
        int rg = m0 + wr * 64 + mi * 16 + g * 4;
        int cg = n0 + wc * 64 + ni * 16 + r16;
        #pragma unroll
        for (int r = 0; r < 4; r++)
          Yf[(size_t)(rg + r) * N + cg] = acc[mi][ni][r];
      }
    }
  }
}

// ---------------- chunked scan over blocked qkvg ----------------
// blocked elem(R,C) = (R>>4)*ROWT + (C>>4)*256 + (C&15)*16 + (R&15)
// step: [sf,ss]' = M_t [sf,ss] + 1.05*u_t*[1,1],  M_t = [[f,.05s],[.05f,s]]

// Pass A: per (chunk j, bh): zero-entry local end state L + chunk 2x2 matrix P
__global__ __launch_bounds__(64) void scan_partA(
    const uint16_t* __restrict__ qkvg, const float* __restrict__ sc,
    float* __restrict__ Lst, float4* __restrict__ Pm)
{
  int j = blockIdx.x, bh = blockIdx.y;
  int b = bh >> 4, h = bh & 15;
  int c = threadIdx.x;
  const int ci = c & 15;
  const size_t tc_k = (size_t)((DD     + h * 64 + c) >> 4) * 256 + ci * 16;
  const size_t tc_v = (size_t)((2 * DD + h * 64 + c) >> 4) * 256 + ci * 16;
  const float* bet = sc + ((size_t)(0 * BB + b) * HH + h) * TT + j * TC;
  const float* fdp = sc + ((size_t)(1 * BB + b) * HH + h) * TT + j * TC;
  const float* sdp = sc + ((size_t)(2 * BB + b) * HH + h) * TT + j * TC;

  float sf = 0.f, ss = 0.f;
  float p00 = 1.f, p01 = 0.f, p10 = 0.f, p11 = 1.f;
  #pragma unroll
  for (int t16 = 0; t16 < 2; ++t16){
    int R0 = b * TT + j * TC + t16 * 16;
    size_t tb = (size_t)(R0 >> 4) * ROWT;
    uint4 kl = *(const uint4*)(qkvg + tb + tc_k);
    uint4 kh = *(const uint4*)(qkvg + tb + tc_k + 8);
    uint4 vl = *(const uint4*)(qkvg + tb + tc_v);
    uint4 vh = *(const uint4*)(qkvg + tb + tc_v + 8);
    const float* bt = bet + t16 * 16;
    const float* ft = fdp + t16 * 16;
    const float* st = sdp + t16 * 16;
    #pragma unroll
    for (int u = 0; u < 16; ++u){
      float kv = (u < 8) ? bfel(kl, u) : bfel(kh, u - 8);
      float vv = (u < 8) ? bfel(vl, u) : bfel(vh, u - 8);
      float btv = bt[u], f = ft[u], s = st[u];
      float uu = 1.05f * btv * kv * vv;
      float bq = 0.05f * s, cq = 0.05f * f;
      float nf = f * sf + bq * ss + uu;
      float ns = cq * sf + s * ss + uu;
      sf = nf; ss = ns;
      float q00 = f * p00 + bq * p10, q01 = f * p01 + bq * p11;
      float q10 = cq * p00 + s * p10, q11 = cq * p01 + s * p11;
      p00 = q00; p01 = q01; p10 = q10; p11 = q11;
    }
  }
  size_t base = ((size_t)bh * NC + j) * 2;
  Lst[(base + 0) * 64 + c] = sf;
  Lst[(base + 1) * 64 + c] = ss;
  if (c == 0) Pm[(size_t)bh * NC + j] = make_float4(p00, p01, p10, p11);
}

// Pass C (with folded lookback): compute entry state E_j from Lst/Pm (all
// written by partA, complete at kernel boundary -- deterministic, no atomics),
// then replay chunk and write og row-major via LDS micro-transpose.
__global__ __launch_bounds__(64) void scan_partC(
    const uint16_t* __restrict__ qkvg, const float* __restrict__ sc,
    const float* __restrict__ Lst, const float4* __restrict__ Pm,
    uint16_t* __restrict__ og)
{
  __shared__ uint16_t ot[16 * 64];
  int j = blockIdx.x, bh = blockIdx.y;
  int b = bh >> 4, h = bh & 15;
  int c = threadIdx.x;
  const int ci = c & 15;

  // forward lookback: E = P_i * E + L_i for i = 0..j-1
  float sf = 0.f, ss = 0.f;
  for (int i = 0; i < j; ++i){
    size_t pbase = ((size_t)bh * NC + i) * 2;
    float lf = Lst[(pbase + 0) * 64 + c];
    float ls = Lst[(pbase + 1) * 64 + c];
    float4 P = Pm[(size_t)bh * NC + i];
    float nf = P.x * sf + P.y * ss + lf;
    float ns = P.z * sf + P.w * ss + ls;
    sf = nf; ss = ns;
  }

  const size_t tc_q = (size_t)((         h * 64 + c) >> 4) * 256 + ci * 16;
  const size_t tc_k = (size_t)((DD     + h * 64 + c) >> 4) * 256 + ci * 16;
  const size_t tc_v = (size_t)((2 * DD + h * 64 + c) >> 4) * 256 + ci * 16;
  const size_t tc_g = (size_t)((3 * DD + h * 64 + c) >> 4) * 256 + ci * 16;
  const float* bet = sc + ((size_t)(0 * BB + b) * HH + h) * TT + j * TC;
  const float* fdp = sc + ((size_t)(1 * BB + b) * HH + h) * TT + j * TC;
  const float* sdp = sc + ((size_t)(2 * BB + b) * HH + h) * TT + j * TC;

  #pragma unroll
  for (int t16 = 0; t16 < 2; ++t16){
    int R0 = b * TT + j * TC + t16 * 16;
    size_t tb = (size_t)(R0 >> 4) * ROWT;
    uint4 ql = *(const uint4*)(qkvg + tb + tc_q);
    uint4 qh = *(const uint4*)(qkvg + tb + tc_q + 8);
    uint4 kl = *(const uint4*)(qkvg + tb + tc_k);
    uint4 kh = *(const uint4*)(qkvg + tb + tc_k + 8);
    uint4 vl = *(const uint4*)(qkvg + tb + tc_v);
    uint4 vh = *(const uint4*)(qkvg + tb + tc_v + 8);
    uint4 gl = *(const uint4*)(qkvg + tb + tc_g);
    uint4 gh = *(const uint4*)(qkvg + tb + tc_g + 8);
    const float* bt = bet + t16 * 16;
    const float* ft = fdp + t16 * 16;
    const float* st = sdp + t16 * 16;
    #pragma unroll
    for (int u = 0; u < 16; ++u){
      float qv = (u < 8) ? bfel(ql, u) : bfel(qh, u - 8);
      float kv = (u < 8) ? bfel(kl, u) : bfel(kh, u - 8);
      float vv = (u < 8) ? bfel(vl, u) : bfel(vh, u - 8);
      float gv = (u < 8) ? bfel(gl, u) : bfel(gh, u - 8);
      float btv = bt[u], f = ft[u], s = st[u];
      sf *= f; ss *= s;
      float o = 0.5f * qv * (sf + ss);
      float uu = btv * kv * vv;
      sf += uu; ss += uu;
      float nf = sf + 0.05f * ss, ns = ss + 0.05f * sf;
      sf = nf; ss = ns;
      ot[u * 64 + c] = f2bf(o * gv);
    }
    __syncthreads();
    {
      int u0 = c >> 3, c8 = c & 7;
      uint4 d0 = *(const uint4*)&ot[u0 * 64 + c8 * 8];
      uint4 d1 = *(const uint4*)&ot[(u0 + 8) * 64 + c8 * 8];
      uint16_t* ob = og + (size_t)R0 * DD + h * 64 + c8 * 8;
      *(uint4*)(ob + (size_t)u0 * DD) = d0;
      *(uint4*)(ob + (size_t)(u0 + 8) * DD) = d1;
    }
    __syncthreads();
  }
}

extern "C" void kernel_launch(void* const* d_in, const int* in_sizes, int n_in,
                              void* d_out, int out_size, void* d_ws, size_t ws_size,
                              hipStream_t stream)
{
  const float* x   = (const float*)d_in[0];
  const float* Wq  = (const float*)d_in[1];
  const float* Wk  = (const float*)d_in[2];
  const float* Wv  = (const float*)d_in[3];
  const float* Wo  = (const float*)d_in[4];
  const float* Wb  = (const float*)d_in[5];
  const float* Wfd = (const float*)d_in[6];
  const float* bfd = (const float*)d_in[7];
  const float* Wsd = (const float*)d_in[8];
  const float* bsd = (const float*)d_in[9];
  const float* Wg  = (const float*)d_in[10];
  float* out = (float*)d_out;

  char* ws = (char*)d_ws;
  size_t off = 0;
  auto alloc = [&](size_t bytes) -> void* {
    void* p = ws + off;
    off += (bytes + 255) & ~(size_t)255;
    return p;
  };

  uint16_t* xb   = (uint16_t*)alloc((size_t)MTOK * DD * 2);   // doubles as ogb later
  uint16_t* wcat = (uint16_t*)alloc((size_t)4 * DD * DD * 2); // Wq|Wk|Wv|Wg
  uint16_t* wob  = (uint16_t*)alloc((size_t)DD * DD * 2);
  uint16_t* qkvg = (uint16_t*)alloc((size_t)MTOK * NQ * 2);   // blocked layout
  float*    sc   = (float*)alloc((size_t)3 * BB * HH * TT * 4);
  float*    Lst  = (float*)alloc((size_t)BH * NC * 2 * 64 * 4);
  float4*   Pm   = (float4*)alloc((size_t)BH * NC * 16);
  uint16_t* ogb  = xb;

  // prep: weight casts + small projections + x cast (one dispatch)
  prep_kernel<<<5120 + MTOK / 16, 256, 0, stream>>>(
      x, Wq, Wk, Wv, Wg, Wo, Wb, Wfd, bfd, Wsd, bsd, wcat, wob, sc, xb);

  // fused q|k|v|g GEMM: [8192,1024] @ [4096,1024]^T -> blocked bf16
  dim3 gq(NQ / 128, MTOK / 128);
  gemm128<0><<<gq, 256, 0, stream>>>(xb, wcat, qkvg, nullptr, NQ, DD);

  // chunked scan: partA (local) then partC (lookback + replay)
  dim3 gs(NC, BH);
  scan_partA<<<gs, 64, 0, stream>>>(qkvg, sc, Lst, Pm);
  scan_partC<<<gs, 64, 0, stream>>>(qkvg, sc, Lst, Pm, ogb);

  // out = (o*g) @ Wo^T, fp32 row-major out
  dim3 go(DD / 128, MTOK / 128);
  gemm128<1><<<go, 256, 0, stream>>>(ogb, wob, nullptr, out, DD, DD);
}

// Round 9
// 189.533 us; speedup vs baseline: 6.1566x; 1.1717x over previous
//
#include <hip/hip_runtime.h>
#include <hip/hip_bf16.h>
#include <stdint.h>

#define BB 4
#define TT 2048
#define DD 1024
#define HH 16
#define MTOK (BB*TT)
#define NQ 4096            // q|k|v|g concat width
#define NW (NQ+128)        // wcat rows incl. small-proj block
#define TC 32              // scan chunk length
#define NC (TT/TC)         // 64 chunks
#define BH (BB*HH)         // 64
#define ROWT (16*NQ)       // elements per 16-row blocked stripe

typedef __bf16 bf16x8 __attribute__((ext_vector_type(8)));
typedef float f32x4 __attribute__((ext_vector_type(4)));

__device__ __forceinline__ uint16_t f2bf(float f){
  uint32_t u = __float_as_uint(f);
  u += 0x7fffu + ((u >> 16) & 1u);
  return (uint16_t)(u >> 16);
}
__device__ __forceinline__ float bf2f(uint32_t h){ return __uint_as_float(h << 16); }
// sigmoid via fast exp + raw v_rcp_f32 (1 ulp) -- avoids precise-div expansion
__device__ __forceinline__ float sigm(float z){
  return __builtin_amdgcn_rcpf(1.f + __expf(-z));
}

__device__ __forceinline__ void gll16(const uint16_t* src, uint16_t* dst){
  __builtin_amdgcn_global_load_lds(
      (const __attribute__((address_space(1))) void*)src,
      (__attribute__((address_space(3))) void*)dst, 16, 0, 0);
}
// extract bf16 element e (static) from a uint4 (8 bf16)
__device__ __forceinline__ float bfel(const uint4& v, int e){
  uint32_t wrd = ((e>>1)==0) ? v.x : ((e>>1)==1) ? v.y : ((e>>1)==2) ? v.z : v.w;
  return bf2f((e&1) ? (wrd >> 16) : (wrd & 0xffffu));
}

// ---------------- prep: pure casts ----------------
// blocks [0,5120): Wq|Wk|Wv|Wg -> wcat rows 0..4095, Wo -> wob  (1 float4/thr)
// blocks [5120,9216): x -> xb  (2 float4/thr)
// blocks [9216,9344): Wb|Wfd|Wsd|zeros -> wcat rows 4096..4223  (4 elems/thr)
__global__ __launch_bounds__(256) void prep_kernel(
    const float* __restrict__ x,
    const float* __restrict__ Wq, const float* __restrict__ Wk,
    const float* __restrict__ Wv, const float* __restrict__ Wg,
    const float* __restrict__ Wo,
    const float* __restrict__ Wb, const float* __restrict__ Wfd,
    const float* __restrict__ Wsd,
    uint16_t* __restrict__ wcat, uint16_t* __restrict__ wob,
    uint16_t* __restrict__ xb)
{
  const int bx = blockIdx.x;
  if (bx < 5120){
    int i = bx * 256 + threadIdx.x;      // float4 index; 262144 per weight
    int wsel = i >> 18;
    int loc = i & 262143;
    const float* src = (wsel == 0) ? Wq : (wsel == 1) ? Wk : (wsel == 2) ? Wv : (wsel == 3) ? Wg : Wo;
    uint16_t* dst = (wsel < 4) ? (wcat + (size_t)wsel * DD * DD) : wob;
    float4 v = ((const float4*)src)[loc];
    ushort4 o;
    o.x = f2bf(v.x); o.y = f2bf(v.y); o.z = f2bf(v.z); o.w = f2bf(v.w);
    ((ushort4*)dst)[loc] = o;
  } else if (bx < 9216){
    int base = (bx - 5120) * 512 + threadIdx.x;
    #pragma unroll
    for (int rep = 0; rep < 2; rep++){
      int loc = base + rep * 256;
      float4 v = ((const float4*)x)[loc];
      ushort4 o;
      o.x = f2bf(v.x); o.y = f2bf(v.y); o.z = f2bf(v.z); o.w = f2bf(v.w);
      ((ushort4*)xb)[loc] = o;
    }
  } else {
    int u = (bx - 9216) * 256 + threadIdx.x;   // 4-elem unit; 256 units/row
    int row = u >> 8;
    int cidx = (u & 255) * 4;
    ushort4 o = {0, 0, 0, 0};
    if (row < 48){
      const float* src = (row < 16) ? (Wb + (size_t)row * DD)
                       : (row < 32) ? (Wfd + (size_t)(row - 16) * DD)
                                    : (Wsd + (size_t)(row - 32) * DD);
      float4 v = *(const float4*)(src + cidx);
      o.x = f2bf(v.x); o.y = f2bf(v.y); o.z = f2bf(v.z); o.w = f2bf(v.w);
    }
    *(ushort4*)(wcat + (size_t)(NQ + row) * DD + cidx) = o;
  }
}

// =============== 128x128 GEMM, BK=64, m97 2-barrier structure (R4-proven) ===============
// X:[M][K], W:[N][K] bf16 row-major. 256 thr = 4 waves (2x2), 64x64 per wave.
// LDS 2x16KB single-buffered. Per-8-row XOR swizzle on 16B chunks:
// LDS chunk p holds logical (row=p>>3, quarter=(p&7)^(row&7)); inverse applied
// to the global source of global_load_lds (rule #21) -> 0 bank conflicts (R4 PMC).
// MODE 0: qkvg+smallproj. col tile n0<3072: silu -> Y (blocked bf16);
//         3072<=n0<4096: sigmoid -> Y; n0==4096: sigm(v+bias) -> sc (f32, [3][B][H][T])
// MODE 1: plain f32 row-major out, no activation.
template<int MODE>
__global__ __launch_bounds__(256) void gemm128(
    const uint16_t* __restrict__ X, const uint16_t* __restrict__ W,
    uint16_t* __restrict__ Y, float* __restrict__ Yf,
    const float* __restrict__ bfd, const float* __restrict__ bsd,
    float* __restrict__ scp, int N, int K)
{
  __shared__ __align__(16) uint16_t lA[128 * 64];
  __shared__ __align__(16) uint16_t lB[128 * 64];
  const int tid = threadIdx.x;
  const int m0 = blockIdx.y * 128, n0 = blockIdx.x * 128;
  const int l = tid & 63, w = tid >> 6;
  const int wr = w >> 1, wc = w & 1;
  const int g = l >> 4, r16 = l & 15;

  // staging: chunk p = n*256 + tid; row = p>>3, logical quarter = (p&7)^(row&7)
  const uint16_t* srcA[4];
  const uint16_t* srcB[4];
  uint16_t* dstA[4];
  uint16_t* dstB[4];
  #pragma unroll
  for (int n = 0; n < 4; n++){
    int p = n * 256 + tid;
    int row = p >> 3;
    int cq = (p & 7) ^ (row & 7);
    srcA[n] = X + (size_t)(m0 + row) * K + cq * 8;
    srcB[n] = W + (size_t)(n0 + row) * K + cq * 8;
    int basechunk = n * 256 + (tid & ~63);     // wave-uniform
    dstA[n] = lA + basechunk * 8;
    dstB[n] = lB + basechunk * 8;
  }

  // frag read offsets (u16 idx): row*64 + ((ks*4+g)^(row&7))*8
  int roA[4][2], roB[4][2];
  #pragma unroll
  for (int i = 0; i < 4; i++)
    #pragma unroll
    for (int ks = 0; ks < 2; ks++){
      roA[i][ks] = (wr * 64 + i * 16 + r16) * 64 + ((ks * 4 + g) ^ (r16 & 7)) * 8;
      roB[i][ks] = (wc * 64 + i * 16 + r16) * 64 + ((ks * 4 + g) ^ (r16 & 7)) * 8;
    }

  f32x4 acc[4][4];
  #pragma unroll
  for (int i = 0; i < 4; i++)
    #pragma unroll
    for (int j = 0; j < 4; j++) acc[i][j] = (f32x4){0.f, 0.f, 0.f, 0.f};

  for (int kt = 0; kt < K; kt += 64){
    __syncthreads();                    // WAR: prior tile reads done
    #pragma unroll
    for (int n = 0; n < 4; n++){
      gll16(srcA[n] + kt, dstA[n]);
      gll16(srcB[n] + kt, dstB[n]);
    }
    __syncthreads();                    // compiler drains vmcnt(0) before barrier

    #pragma unroll
    for (int ks = 0; ks < 2; ks++){
      bf16x8 af[4], bw[4];
      #pragma unroll
      for (int mi = 0; mi < 4; mi++) af[mi] = *(const bf16x8*)(lA + roA[mi][ks]);
      #pragma unroll
      for (int ni = 0; ni < 4; ni++) bw[ni] = *(const bf16x8*)(lB + roB[ni][ks]);
      #pragma unroll
      for (int mi = 0; mi < 4; mi++)
        #pragma unroll
        for (int ni = 0; ni < 4; ni++)
          acc[mi][ni] = __builtin_amdgcn_mfma_f32_16x16x32_bf16(af[mi], bw[ni], acc[mi][ni], 0, 0, 0);
    }
  }

  // C/D layout: col=lane&15, row=(lane>>4)*4+reg  [m89-verified]
  if (MODE == 0){
    if (n0 < NQ){
      const bool dosig = (n0 >= 3 * DD);
      #pragma unroll
      for (int mi = 0; mi < 4; mi++){
        const int R0 = m0 + wr * 64 + mi * 16;
        const size_t rbase = (size_t)(R0 >> 4) * ROWT;
        #pragma unroll
        for (int ni = 0; ni < 4; ni++){
          const int C0 = n0 + wc * 64 + ni * 16;
          f32x4 v = acc[mi][ni];
          float o[4];
          #pragma unroll
          for (int r = 0; r < 4; r++){
            float xx = v[r];
            o[r] = dosig ? sigm(xx) : xx * sigm(xx);
          }
          uint2 pk;
          pk.x = (uint32_t)f2bf(o[0]) | ((uint32_t)f2bf(o[1]) << 16);
          pk.y = (uint32_t)f2bf(o[2]) | ((uint32_t)f2bf(o[3]) << 16);
          size_t off = rbase + (size_t)(C0 >> 4) * 256 + (size_t)r16 * 16 + g * 4;
          *(uint2*)(Y + off) = pk;
        }
      }
    } else {
      // small-proj tile: cols 0..47 -> sc[grp][b][h][t] (f32), rest discarded
      #pragma unroll
      for (int ni = 0; ni < 4; ni++){
        const int cc0 = wc * 64 + ni * 16;          // col block within tile
        const int grp = cc0 >> 4;
        if (grp < 3){
          const int h = r16;
          const float bias = (grp == 0) ? 0.f : (grp == 1) ? bfd[h] : bsd[h];
          #pragma unroll
          for (int mi = 0; mi < 4; mi++){
            const int R0 = m0 + wr * 64 + mi * 16 + g * 4;  // token rows R0..R0+3
            const int b = R0 >> 11, t = R0 & (TT - 1);
            f32x4 v = acc[mi][ni];
            float4 o;
            o.x = sigm(v[0] + bias);
            o.y = sigm(v[1] + bias);
            o.z = sigm(v[2] + bias);
            o.w = sigm(v[3] + bias);
            *(float4*)(scp + (((size_t)grp * BB + b) * HH + h) * TT + t) = o;
          }
        }
      }
    }
  } else {
    #pragma unroll
    for (int mi = 0; mi < 4; mi++){
      #pragma unroll
      for (int ni = 0; ni < 4; ni++){
        int rg = m0 + wr * 64 + mi * 16 + g * 4;
        int cg = n0 + wc * 64 + ni * 16 + r16;
        #pragma unroll
        for (int r = 0; r < 4; r++)
          Yf[(size_t)(rg + r) * N + cg] = acc[mi][ni][r];
      }
    }
  }
}

// ---------------- chunked scan over blocked qkvg ----------------
// blocked elem(R,C) = (R>>4)*ROWT + (C>>4)*256 + (C&15)*16 + (R&15)
// step: [sf,ss]' = M_t [sf,ss] + 1.05*u_t*[1,1],  M_t = [[f,.05s],[.05f,s]]

// Pass A: per (chunk j, bh): zero-entry local end state L + chunk 2x2 matrix P
__global__ __launch_bounds__(64) void scan_partA(
    const uint16_t* __restrict__ qkvg, const float* __restrict__ sc,
    float* __restrict__ Lst, float4* __restrict__ Pm)
{
  int j = blockIdx.x, bh = blockIdx.y;
  int b = bh >> 4, h = bh & 15;
  int c = threadIdx.x;
  const int ci = c & 15;
  const size_t tc_k = (size_t)((DD     + h * 64 + c) >> 4) * 256 + ci * 16;
  const size_t tc_v = (size_t)((2 * DD + h * 64 + c) >> 4) * 256 + ci * 16;
  const float* bet = sc + ((size_t)(0 * BB + b) * HH + h) * TT + j * TC;
  const float* fdp = sc + ((size_t)(1 * BB + b) * HH + h) * TT + j * TC;
  const float* sdp = sc + ((size_t)(2 * BB + b) * HH + h) * TT + j * TC;

  float sf = 0.f, ss = 0.f;
  float p00 = 1.f, p01 = 0.f, p10 = 0.f, p11 = 1.f;
  #pragma unroll
  for (int t16 = 0; t16 < 2; ++t16){
    int R0 = b * TT + j * TC + t16 * 16;
    size_t tb = (size_t)(R0 >> 4) * ROWT;
    uint4 kl = *(const uint4*)(qkvg + tb + tc_k);
    uint4 kh = *(const uint4*)(qkvg + tb + tc_k + 8);
    uint4 vl = *(const uint4*)(qkvg + tb + tc_v);
    uint4 vh = *(const uint4*)(qkvg + tb + tc_v + 8);
    const float* bt = bet + t16 * 16;
    const float* ft = fdp + t16 * 16;
    const float* st = sdp + t16 * 16;
    #pragma unroll
    for (int u = 0; u < 16; ++u){
      float kv = (u < 8) ? bfel(kl, u) : bfel(kh, u - 8);
      float vv = (u < 8) ? bfel(vl, u) : bfel(vh, u - 8);
      float btv = bt[u], f = ft[u], s = st[u];
      float uu = 1.05f * btv * kv * vv;
      float bq = 0.05f * s, cq = 0.05f * f;
      float nf = f * sf + bq * ss + uu;
      float ns = cq * sf + s * ss + uu;
      sf = nf; ss = ns;
      float q00 = f * p00 + bq * p10, q01 = f * p01 + bq * p11;
      float q10 = cq * p00 + s * p10, q11 = cq * p01 + s * p11;
      p00 = q00; p01 = q01; p10 = q10; p11 = q11;
    }
  }
  size_t base = ((size_t)bh * NC + j) * 2;
  Lst[(base + 0) * 64 + c] = sf;
  Lst[(base + 1) * 64 + c] = ss;
  if (c == 0) Pm[(size_t)bh * NC + j] = make_float4(p00, p01, p10, p11);
}

// Pass C (with folded lookback): compute entry state E_j from Lst/Pm (all
// written by partA, complete at kernel boundary -- deterministic, no atomics),
// then replay chunk and write og row-major via LDS micro-transpose.
__global__ __launch_bounds__(64) void scan_partC(
    const uint16_t* __restrict__ qkvg, const float* __restrict__ sc,
    const float* __restrict__ Lst, const float4* __restrict__ Pm,
    uint16_t* __restrict__ og)
{
  __shared__ uint16_t ot[16 * 64];
  int j = blockIdx.x, bh = blockIdx.y;
  int b = bh >> 4, h = bh & 15;
  int c = threadIdx.x;
  const int ci = c & 15;

  // forward lookback: E = P_i * E + L_i for i = 0..j-1
  float sf = 0.f, ss = 0.f;
  for (int i = 0; i < j; ++i){
    size_t pbase = ((size_t)bh * NC + i) * 2;
    float lf = Lst[(pbase + 0) * 64 + c];
    float ls = Lst[(pbase + 1) * 64 + c];
    float4 P = Pm[(size_t)bh * NC + i];
    float nf = P.x * sf + P.y * ss + lf;
    float ns = P.z * sf + P.w * ss + ls;
    sf = nf; ss = ns;
  }

  const size_t tc_q = (size_t)((         h * 64 + c) >> 4) * 256 + ci * 16;
  const size_t tc_k = (size_t)((DD     + h * 64 + c) >> 4) * 256 + ci * 16;
  const size_t tc_v = (size_t)((2 * DD + h * 64 + c) >> 4) * 256 + ci * 16;
  const size_t tc_g = (size_t)((3 * DD + h * 64 + c) >> 4) * 256 + ci * 16;
  const float* bet = sc + ((size_t)(0 * BB + b) * HH + h) * TT + j * TC;
  const float* fdp = sc + ((size_t)(1 * BB + b) * HH + h) * TT + j * TC;
  const float* sdp = sc + ((size_t)(2 * BB + b) * HH + h) * TT + j * TC;

  #pragma unroll
  for (int t16 = 0; t16 < 2; ++t16){
    int R0 = b * TT + j * TC + t16 * 16;
    size_t tb = (size_t)(R0 >> 4) * ROWT;
    uint4 ql = *(const uint4*)(qkvg + tb + tc_q);
    uint4 qh = *(const uint4*)(qkvg + tb + tc_q + 8);
    uint4 kl = *(const uint4*)(qkvg + tb + tc_k);
    uint4 kh = *(const uint4*)(qkvg + tb + tc_k + 8);
    uint4 vl = *(const uint4*)(qkvg + tb + tc_v);
    uint4 vh = *(const uint4*)(qkvg + tb + tc_v + 8);
    uint4 gl = *(const uint4*)(qkvg + tb + tc_g);
    uint4 gh = *(const uint4*)(qkvg + tb + tc_g + 8);
    const float* bt = bet + t16 * 16;
    const float* ft = fdp + t16 * 16;
    const float* st = sdp + t16 * 16;
    #pragma unroll
    for (int u = 0; u < 16; ++u){
      float qv = (u < 8) ? bfel(ql, u) : bfel(qh, u - 8);
      float kv = (u < 8) ? bfel(kl, u) : bfel(kh, u - 8);
      float vv = (u < 8) ? bfel(vl, u) : bfel(vh, u - 8);
      float gv = (u < 8) ? bfel(gl, u) : bfel(gh, u - 8);
      float btv = bt[u], f = ft[u], s = st[u];
      sf *= f; ss *= s;
      float o = 0.5f * qv * (sf + ss);
      float uu = btv * kv * vv;
      sf += uu; ss += uu;
      float nf = sf + 0.05f * ss, ns = ss + 0.05f * sf;
      sf = nf; ss = ns;
      ot[u * 64 + c] = f2bf(o * gv);
    }
    __syncthreads();
    {
      int u0 = c >> 3, c8 = c & 7;
      uint4 d0 = *(const uint4*)&ot[u0 * 64 + c8 * 8];
      uint4 d1 = *(const uint4*)&ot[(u0 + 8) * 64 + c8 * 8];
      uint16_t* ob = og + (size_t)R0 * DD + h * 64 + c8 * 8;
      *(uint4*)(ob + (size_t)u0 * DD) = d0;
      *(uint4*)(ob + (size_t)(u0 + 8) * DD) = d1;
    }
    __syncthreads();
  }
}

extern "C" void kernel_launch(void* const* d_in, const int* in_sizes, int n_in,
                              void* d_out, int out_size, void* d_ws, size_t ws_size,
                              hipStream_t stream)
{
  const float* x   = (const float*)d_in[0];
  const float* Wq  = (const float*)d_in[1];
  const float* Wk  = (const float*)d_in[2];
  const float* Wv  = (const float*)d_in[3];
  const float* Wo  = (const float*)d_in[4];
  const float* Wb  = (const float*)d_in[5];
  const float* Wfd = (const float*)d_in[6];
  const float* bfd = (const float*)d_in[7];
  const float* Wsd = (const float*)d_in[8];
  const float* bsd = (const float*)d_in[9];
  const float* Wg  = (const float*)d_in[10];
  float* out = (float*)d_out;

  char* ws = (char*)d_ws;
  size_t off = 0;
  auto alloc = [&](size_t bytes) -> void* {
    void* p = ws + off;
    off += (bytes + 255) & ~(size_t)255;
    return p;
  };

  uint16_t* xb   = (uint16_t*)alloc((size_t)MTOK * DD * 2);   // doubles as ogb later
  uint16_t* wcat = (uint16_t*)alloc((size_t)NW * DD * 2);     // Wq|Wk|Wv|Wg|small(128)
  uint16_t* wob  = (uint16_t*)alloc((size_t)DD * DD * 2);
  uint16_t* qkvg = (uint16_t*)alloc((size_t)MTOK * NQ * 2);   // blocked layout
  float*    sc   = (float*)alloc((size_t)3 * BB * HH * TT * 4);
  float*    Lst  = (float*)alloc((size_t)BH * NC * 2 * 64 * 4);
  float4*   Pm   = (float4*)alloc((size_t)BH * NC * 16);
  uint16_t* ogb  = xb;

  // prep: all casts (weights, x, small-proj weight block) in one dispatch
  prep_kernel<<<9344, 256, 0, stream>>>(
      x, Wq, Wk, Wv, Wg, Wo, Wb, Wfd, Wsd, wcat, wob, xb);

  // fused q|k|v|g|smallproj GEMM: [8192,1024] @ [4224,1024]^T
  dim3 gq(NQ / 128 + 1, MTOK / 128);
  gemm128<0><<<gq, 256, 0, stream>>>(xb, wcat, qkvg, nullptr, bfd, bsd, sc, NQ, DD);

  // chunked scan: partA (local) then partC (lookback + replay)
  dim3 gs(NC, BH);
  scan_partA<<<gs, 64, 0, stream>>>(qkvg, sc, Lst, Pm);
  scan_partC<<<gs, 64, 0, stream>>>(qkvg, sc, Lst, Pm, ogb);

  // out = (o*g) @ Wo^T, fp32 row-major out
  dim3 go(DD / 128, MTOK / 128);
  gemm128<1><<<go, 256, 0, stream>>>(ogb, wob, nullptr, out, bfd, bsd, nullptr, DD, DD);
}

// Round 10
// 176.849 us; speedup vs baseline: 6.5982x; 1.0717x over previous
//
#include <hip/hip_runtime.h>
#include <hip/hip_bf16.h>
#include <stdint.h>

#define BB 4
#define TT 2048
#define DD 1024
#define HH 16
#define MTOK (BB*TT)
#define NQ 4096            // q|k|v|g concat width
#define NW (NQ+128)        // wcat rows incl. small-proj block
#define TC 32              // scan chunk length
#define NC (TT/TC)         // 64 chunks
#define BH (BB*HH)         // 64
#define ROWT (16*NQ)       // elements per 16-row blocked stripe

typedef __bf16 bf16x8 __attribute__((ext_vector_type(8)));
typedef float f32x4 __attribute__((ext_vector_type(4)));

__device__ __forceinline__ uint16_t f2bf(float f){
  uint32_t u = __float_as_uint(f);
  u += 0x7fffu + ((u >> 16) & 1u);
  return (uint16_t)(u >> 16);
}
__device__ __forceinline__ float bf2f(uint32_t h){ return __uint_as_float(h << 16); }
// sigmoid via fast exp + raw v_rcp_f32 (1 ulp) -- avoids precise-div expansion
__device__ __forceinline__ float sigm(float z){
  return __builtin_amdgcn_rcpf(1.f + __expf(-z));
}

__device__ __forceinline__ void gll16(const uint16_t* src, uint16_t* dst){
  __builtin_amdgcn_global_load_lds(
      (const __attribute__((address_space(1))) void*)src,
      (__attribute__((address_space(3))) void*)dst, 16, 0, 0);
}
// extract bf16 element e (static) from a uint4 (8 bf16)
__device__ __forceinline__ float bfel(const uint4& v, int e){
  uint32_t wrd = ((e>>1)==0) ? v.x : ((e>>1)==1) ? v.y : ((e>>1)==2) ? v.z : v.w;
  return bf2f((e&1) ? (wrd >> 16) : (wrd & 0xffffu));
}

// ---------------- prep: pure casts ----------------
// blocks [0,5120): Wq|Wk|Wv|Wg -> wcat rows 0..4095, Wo -> wob  (1 float4/thr)
// blocks [5120,9216): x -> xb  (2 float4/thr)
// blocks [9216,9344): Wb|Wfd|Wsd|zeros -> wcat rows 4096..4223  (4 elems/thr)
__global__ __launch_bounds__(256) void prep_kernel(
    const float* __restrict__ x,
    const float* __restrict__ Wq, const float* __restrict__ Wk,
    const float* __restrict__ Wv, const float* __restrict__ Wg,
    const float* __restrict__ Wo,
    const float* __restrict__ Wb, const float* __restrict__ Wfd,
    const float* __restrict__ Wsd,
    uint16_t* __restrict__ wcat, uint16_t* __restrict__ wob,
    uint16_t* __restrict__ xb)
{
  const int bx = blockIdx.x;
  if (bx < 5120){
    int i = bx * 256 + threadIdx.x;      // float4 index; 262144 per weight
    int wsel = i >> 18;
    int loc = i & 262143;
    const float* src = (wsel == 0) ? Wq : (wsel == 1) ? Wk : (wsel == 2) ? Wv : (wsel == 3) ? Wg : Wo;
    uint16_t* dst = (wsel < 4) ? (wcat + (size_t)wsel * DD * DD) : wob;
    float4 v = ((const float4*)src)[loc];
    ushort4 o;
    o.x = f2bf(v.x); o.y = f2bf(v.y); o.z = f2bf(v.z); o.w = f2bf(v.w);
    ((ushort4*)dst)[loc] = o;
  } else if (bx < 9216){
    int base = (bx - 5120) * 512 + threadIdx.x;
    #pragma unroll
    for (int rep = 0; rep < 2; rep++){
      int loc = base + rep * 256;
      float4 v = ((const float4*)x)[loc];
      ushort4 o;
      o.x = f2bf(v.x); o.y = f2bf(v.y); o.z = f2bf(v.z); o.w = f2bf(v.w);
      ((ushort4*)xb)[loc] = o;
    }
  } else {
    int u = (bx - 9216) * 256 + threadIdx.x;   // 4-elem unit; 256 units/row
    int row = u >> 8;
    int cidx = (u & 255) * 4;
    ushort4 o = {0, 0, 0, 0};
    if (row < 48){
      const float* src = (row < 16) ? (Wb + (size_t)row * DD)
                       : (row < 32) ? (Wfd + (size_t)(row - 16) * DD)
                                    : (Wsd + (size_t)(row - 32) * DD);
      float4 v = *(const float4*)(src + cidx);
      o.x = f2bf(v.x); o.y = f2bf(v.y); o.z = f2bf(v.z); o.w = f2bf(v.w);
    }
    *(ushort4*)(wcat + (size_t)(NQ + row) * DD + cidx) = o;
  }
}

// =============== 128x128 GEMM, BK=64, m97 2-barrier structure (R4-proven) ===============
// X:[M][K], W:[N][K] bf16 row-major. 256 thr = 4 waves (2x2), 64x64 per wave.
// LDS 2x16KB single-buffered. Per-8-row XOR swizzle on 16B chunks -> 0 conflicts.
// T1 XCD supertile swizzle (1D grid, nwg % 8 == 0): xcd = bid&7 owns m-tiles
// [8*xcd, 8*xcd+8) x all n-tiles, n-major: loc = bid>>3; n = loc>>3; ml = loc&7.
// Per-XCD: 2MB A-panels L2-resident; B panel shared by 8 consecutive blocks.
// MODE 0: qkvg+smallproj. n0<3072: silu -> Y (blocked bf16);
//         3072<=n0<4096: sigmoid -> Y; n0==4096: sigm(v+bias) -> sc (f32 [3][B][H][T])
// MODE 1: plain f32 row-major out, no activation.
template<int MODE>
__global__ __launch_bounds__(256) void gemm128(
    const uint16_t* __restrict__ X, const uint16_t* __restrict__ W,
    uint16_t* __restrict__ Y, float* __restrict__ Yf,
    const float* __restrict__ bfd, const float* __restrict__ bsd,
    float* __restrict__ scp, int N, int K)
{
  __shared__ __align__(16) uint16_t lA[128 * 64];
  __shared__ __align__(16) uint16_t lB[128 * 64];
  const int tid = threadIdx.x;
  const int bid = blockIdx.x;
  const int xcd = bid & 7, loc = bid >> 3;
  const int m0 = (xcd * 8 + (loc & 7)) * 128;     // M fixed: 64 m-tiles = 8 XCDs x 8
  const int n0 = (loc >> 3) * 128;
  const int l = tid & 63, w = tid >> 6;
  const int wr = w >> 1, wc = w & 1;
  const int g = l >> 4, r16 = l & 15;

  // staging: chunk p = n*256 + tid; row = p>>3, logical quarter = (p&7)^(row&7)
  const uint16_t* srcA[4];
  const uint16_t* srcB[4];
  uint16_t* dstA[4];
  uint16_t* dstB[4];
  #pragma unroll
  for (int n = 0; n < 4; n++){
    int p = n * 256 + tid;
    int row = p >> 3;
    int cq = (p & 7) ^ (row & 7);
    srcA[n] = X + (size_t)(m0 + row) * K + cq * 8;
    srcB[n] = W + (size_t)(n0 + row) * K + cq * 8;
    int basechunk = n * 256 + (tid & ~63);     // wave-uniform
    dstA[n] = lA + basechunk * 8;
    dstB[n] = lB + basechunk * 8;
  }

  // frag read offsets (u16 idx): row*64 + ((ks*4+g)^(row&7))*8
  int roA[4][2], roB[4][2];
  #pragma unroll
  for (int i = 0; i < 4; i++)
    #pragma unroll
    for (int ks = 0; ks < 2; ks++){
      roA[i][ks] = (wr * 64 + i * 16 + r16) * 64 + ((ks * 4 + g) ^ (r16 & 7)) * 8;
      roB[i][ks] = (wc * 64 + i * 16 + r16) * 64 + ((ks * 4 + g) ^ (r16 & 7)) * 8;
    }

  f32x4 acc[4][4];
  #pragma unroll
  for (int i = 0; i < 4; i++)
    #pragma unroll
    for (int j = 0; j < 4; j++) acc[i][j] = (f32x4){0.f, 0.f, 0.f, 0.f};

  for (int kt = 0; kt < K; kt += 64){
    __syncthreads();                    // WAR: prior tile reads done
    #pragma unroll
    for (int n = 0; n < 4; n++){
      gll16(srcA[n] + kt, dstA[n]);
      gll16(srcB[n] + kt, dstB[n]);
    }
    __syncthreads();                    // compiler drains vmcnt(0) before barrier

    #pragma unroll
    for (int ks = 0; ks < 2; ks++){
      bf16x8 af[4], bw[4];
      #pragma unroll
      for (int mi = 0; mi < 4; mi++) af[mi] = *(const bf16x8*)(lA + roA[mi][ks]);
      #pragma unroll
      for (int ni = 0; ni < 4; ni++) bw[ni] = *(const bf16x8*)(lB + roB[ni][ks]);
      #pragma unroll
      for (int mi = 0; mi < 4; mi++)
        #pragma unroll
        for (int ni = 0; ni < 4; ni++)
          acc[mi][ni] = __builtin_amdgcn_mfma_f32_16x16x32_bf16(af[mi], bw[ni], acc[mi][ni], 0, 0, 0);
    }
  }

  // C/D layout: col=lane&15, row=(lane>>4)*4+reg  [m89-verified]
  if (MODE == 0){
    if (n0 < NQ){
      const bool dosig = (n0 >= 3 * DD);
      #pragma unroll
      for (int mi = 0; mi < 4; mi++){
        const int R0 = m0 + wr * 64 + mi * 16;
        const size_t rbase = (size_t)(R0 >> 4) * ROWT;
        #pragma unroll
        for (int ni = 0; ni < 4; ni++){
          const int C0 = n0 + wc * 64 + ni * 16;
          f32x4 v = acc[mi][ni];
          float o[4];
          #pragma unroll
          for (int r = 0; r < 4; r++){
            float xx = v[r];
            o[r] = dosig ? sigm(xx) : xx * sigm(xx);
          }
          uint2 pk;
          pk.x = (uint32_t)f2bf(o[0]) | ((uint32_t)f2bf(o[1]) << 16);
          pk.y = (uint32_t)f2bf(o[2]) | ((uint32_t)f2bf(o[3]) << 16);
          size_t off = rbase + (size_t)(C0 >> 4) * 256 + (size_t)r16 * 16 + g * 4;
          *(uint2*)(Y + off) = pk;
        }
      }
    } else {
      // small-proj tile: cols 0..47 -> sc[grp][b][h][t] (f32), rest discarded
      #pragma unroll
      for (int ni = 0; ni < 4; ni++){
        const int cc0 = wc * 64 + ni * 16;          // col block within tile
        const int grp = cc0 >> 4;
        if (grp < 3){
          const int h = r16;
          const float bias = (grp == 0) ? 0.f : (grp == 1) ? bfd[h] : bsd[h];
          #pragma unroll
          for (int mi = 0; mi < 4; mi++){
            const int R0 = m0 + wr * 64 + mi * 16 + g * 4;  // token rows R0..R0+3
            const int b = R0 >> 11, t = R0 & (TT - 1);
            f32x4 v = acc[mi][ni];
            float4 o;
            o.x = sigm(v[0] + bias);
            o.y = sigm(v[1] + bias);
            o.z = sigm(v[2] + bias);
            o.w = sigm(v[3] + bias);
            *(float4*)(scp + (((size_t)grp * BB + b) * HH + h) * TT + t) = o;
          }
        }
      }
    }
  } else {
    #pragma unroll
    for (int mi = 0; mi < 4; mi++){
      #pragma unroll
      for (int ni = 0; ni < 4; ni++){
        int rg = m0 + wr * 64 + mi * 16 + g * 4;
        int cg = n0 + wc * 64 + ni * 16 + r16;
        #pragma unroll
        for (int r = 0; r < 4; r++)
          Yf[(size_t)(rg + r) * N + cg] = acc[mi][ni][r];
      }
    }
  }
}

// ---------------- chunked scan over blocked qkvg ----------------
// blocked elem(R,C) = (R>>4)*ROWT + (C>>4)*256 + (C&15)*16 + (R&15)
// step: [sf,ss]' = M_t [sf,ss] + 1.05*u_t*[1,1],  M_t = [[f,.05s],[.05f,s]]

// Pass A: per (chunk j, bh): zero-entry local end state L + chunk 2x2 matrix P
__global__ __launch_bounds__(64) void scan_partA(
    const uint16_t* __restrict__ qkvg, const float* __restrict__ sc,
    float* __restrict__ Lst, float4* __restrict__ Pm)
{
  int j = blockIdx.x, bh = blockIdx.y;
  int b = bh >> 4, h = bh & 15;
  int c = threadIdx.x;
  const int ci = c & 15;
  const size_t tc_k = (size_t)((DD     + h * 64 + c) >> 4) * 256 + ci * 16;
  const size_t tc_v = (size_t)((2 * DD + h * 64 + c) >> 4) * 256 + ci * 16;
  const float* bet = sc + ((size_t)(0 * BB + b) * HH + h) * TT + j * TC;
  const float* fdp = sc + ((size_t)(1 * BB + b) * HH + h) * TT + j * TC;
  const float* sdp = sc + ((size_t)(2 * BB + b) * HH + h) * TT + j * TC;

  float sf = 0.f, ss = 0.f;
  float p00 = 1.f, p01 = 0.f, p10 = 0.f, p11 = 1.f;
  #pragma unroll
  for (int t16 = 0; t16 < 2; ++t16){
    int R0 = b * TT + j * TC + t16 * 16;
    size_t tb = (size_t)(R0 >> 4) * ROWT;
    uint4 kl = *(const uint4*)(qkvg + tb + tc_k);
    uint4 kh = *(const uint4*)(qkvg + tb + tc_k + 8);
    uint4 vl = *(const uint4*)(qkvg + tb + tc_v);
    uint4 vh = *(const uint4*)(qkvg + tb + tc_v + 8);
    const float* bt = bet + t16 * 16;
    const float* ft = fdp + t16 * 16;
    const float* st = sdp + t16 * 16;
    #pragma unroll
    for (int u = 0; u < 16; ++u){
      float kv = (u < 8) ? bfel(kl, u) : bfel(kh, u - 8);
      float vv = (u < 8) ? bfel(vl, u) : bfel(vh, u - 8);
      float btv = bt[u], f = ft[u], s = st[u];
      float uu = 1.05f * btv * kv * vv;
      float bq = 0.05f * s, cq = 0.05f * f;
      float nf = f * sf + bq * ss + uu;
      float ns = cq * sf + s * ss + uu;
      sf = nf; ss = ns;
      float q00 = f * p00 + bq * p10, q01 = f * p01 + bq * p11;
      float q10 = cq * p00 + s * p10, q11 = cq * p01 + s * p11;
      p00 = q00; p01 = q01; p10 = q10; p11 = q11;
    }
  }
  size_t base = ((size_t)bh * NC + j) * 2;
  Lst[(base + 0) * 64 + c] = sf;
  Lst[(base + 1) * 64 + c] = ss;
  if (c == 0) Pm[(size_t)bh * NC + j] = make_float4(p00, p01, p10, p11);
}

// Pass C (with folded lookback): compute entry state E_j from Lst/Pm (all
// written by partA, complete at kernel boundary -- deterministic, no atomics),
// then replay chunk and write og row-major via LDS micro-transpose.
__global__ __launch_bounds__(64) void scan_partC(
    const uint16_t* __restrict__ qkvg, const float* __restrict__ sc,
    const float* __restrict__ Lst, const float4* __restrict__ Pm,
    uint16_t* __restrict__ og)
{
  __shared__ uint16_t ot[16 * 64];
  int j = blockIdx.x, bh = blockIdx.y;
  int b = bh >> 4, h = bh & 15;
  int c = threadIdx.x;
  const int ci = c & 15;

  // forward lookback: E = P_i * E + L_i for i = 0..j-1
  float sf = 0.f, ss = 0.f;
  for (int i = 0; i < j; ++i){
    size_t pbase = ((size_t)bh * NC + i) * 2;
    float lf = Lst[(pbase + 0) * 64 + c];
    float ls = Lst[(pbase + 1) * 64 + c];
    float4 P = Pm[(size_t)bh * NC + i];
    float nf = P.x * sf + P.y * ss + lf;
    float ns = P.z * sf + P.w * ss + ls;
    sf = nf; ss = ns;
  }

  const size_t tc_q = (size_t)((         h * 64 + c) >> 4) * 256 + ci * 16;
  const size_t tc_k = (size_t)((DD     + h * 64 + c) >> 4) * 256 + ci * 16;
  const size_t tc_v = (size_t)((2 * DD + h * 64 + c) >> 4) * 256 + ci * 16;
  const size_t tc_g = (size_t)((3 * DD + h * 64 + c) >> 4) * 256 + ci * 16;
  const float* bet = sc + ((size_t)(0 * BB + b) * HH + h) * TT + j * TC;
  const float* fdp = sc + ((size_t)(1 * BB + b) * HH + h) * TT + j * TC;
  const float* sdp = sc + ((size_t)(2 * BB + b) * HH + h) * TT + j * TC;

  #pragma unroll
  for (int t16 = 0; t16 < 2; ++t16){
    int R0 = b * TT + j * TC + t16 * 16;
    size_t tb = (size_t)(R0 >> 4) * ROWT;
    uint4 ql = *(const uint4*)(qkvg + tb + tc_q);
    uint4 qh = *(const uint4*)(qkvg + tb + tc_q + 8);
    uint4 kl = *(const uint4*)(qkvg + tb + tc_k);
    uint4 kh = *(const uint4*)(qkvg + tb + tc_k + 8);
    uint4 vl = *(const uint4*)(qkvg + tb + tc_v);
    uint4 vh = *(const uint4*)(qkvg + tb + tc_v + 8);
    uint4 gl = *(const uint4*)(qkvg + tb + tc_g);
    uint4 gh = *(const uint4*)(qkvg + tb + tc_g + 8);
    const float* bt = bet + t16 * 16;
    const float* ft = fdp + t16 * 16;
    const float* st = sdp + t16 * 16;
    #pragma unroll
    for (int u = 0; u < 16; ++u){
      float qv = (u < 8) ? bfel(ql, u) : bfel(qh, u - 8);
      float kv = (u < 8) ? bfel(kl, u) : bfel(kh, u - 8);
      float vv = (u < 8) ? bfel(vl, u) : bfel(vh, u - 8);
      float gv = (u < 8) ? bfel(gl, u) : bfel(gh, u - 8);
      float btv = bt[u], f = ft[u], s = st[u];
      sf *= f; ss *= s;
      float o = 0.5f * qv * (sf + ss);
      float uu = btv * kv * vv;
      sf += uu; ss += uu;
      float nf = sf + 0.05f * ss, ns = ss + 0.05f * sf;
      sf = nf; ss = ns;
      ot[u * 64 + c] = f2bf(o * gv);
    }
    __syncthreads();
    {
      int u0 = c >> 3, c8 = c & 7;
      uint4 d0 = *(const uint4*)&ot[u0 * 64 + c8 * 8];
      uint4 d1 = *(const uint4*)&ot[(u0 + 8) * 64 + c8 * 8];
      uint16_t* ob = og + (size_t)R0 * DD + h * 64 + c8 * 8;
      *(uint4*)(ob + (size_t)u0 * DD) = d0;
      *(uint4*)(ob + (size_t)(u0 + 8) * DD) = d1;
    }
    __syncthreads();
  }
}

extern "C" void kernel_launch(void* const* d_in, const int* in_sizes, int n_in,
                              void* d_out, int out_size, void* d_ws, size_t ws_size,
                              hipStream_t stream)
{
  const float* x   = (const float*)d_in[0];
  const float* Wq  = (const float*)d_in[1];
  const float* Wk  = (const float*)d_in[2];
  const float* Wv  = (const float*)d_in[3];
  const float* Wo  = (const float*)d_in[4];
  const float* Wb  = (const float*)d_in[5];
  const float* Wfd = (const float*)d_in[6];
  const float* bfd = (const float*)d_in[7];
  const float* Wsd = (const float*)d_in[8];
  const float* bsd = (const float*)d_in[9];
  const float* Wg  = (const float*)d_in[10];
  float* out = (float*)d_out;

  char* ws = (char*)d_ws;
  size_t off = 0;
  auto alloc = [&](size_t bytes) -> void* {
    void* p = ws + off;
    off += (bytes + 255) & ~(size_t)255;
    return p;
  };

  uint16_t* xb   = (uint16_t*)alloc((size_t)MTOK * DD * 2);   // doubles as ogb later
  uint16_t* wcat = (uint16_t*)alloc((size_t)NW * DD * 2);     // Wq|Wk|Wv|Wg|small(128)
  uint16_t* wob  = (uint16_t*)alloc((size_t)DD * DD * 2);
  uint16_t* qkvg = (uint16_t*)alloc((size_t)MTOK * NQ * 2);   // blocked layout
  float*    sc   = (float*)alloc((size_t)3 * BB * HH * TT * 4);
  float*    Lst  = (float*)alloc((size_t)BH * NC * 2 * 64 * 4);
  float4*   Pm   = (float4*)alloc((size_t)BH * NC * 16);
  uint16_t* ogb  = xb;

  // prep: all casts (weights, x, small-proj weight block) in one dispatch
  prep_kernel<<<9344, 256, 0, stream>>>(
      x, Wq, Wk, Wv, Wg, Wo, Wb, Wfd, Wsd, wcat, wob, xb);

  // fused q|k|v|g|smallproj GEMM: [8192,1024] @ [4224,1024]^T, T1-swizzled 1D grid
  gemm128<0><<<(NQ / 128 + 1) * (MTOK / 128), 256, 0, stream>>>(
      xb, wcat, qkvg, nullptr, bfd, bsd, sc, NQ, DD);

  // chunked scan: partA (local) then partC (lookback + replay)
  dim3 gs(NC, BH);
  scan_partA<<<gs, 64, 0, stream>>>(qkvg, sc, Lst, Pm);
  scan_partC<<<gs, 64, 0, stream>>>(qkvg, sc, Lst, Pm, ogb);

  // out = (o*g) @ Wo^T, fp32 row-major out, T1-swizzled 1D grid
  gemm128<1><<<(DD / 128) * (MTOK / 128), 256, 0, stream>>>(
      ogb, wob, nullptr, out, bfd, bsd, nullptr, DD, DD);
}

// Round 11
// 171.211 us; speedup vs baseline: 6.8155x; 1.0329x over previous
//
#include <hip/hip_runtime.h>
#include <hip/hip_bf16.h>
#include <stdint.h>

#define BB 4
#define TT 2048
#define DD 1024
#define HH 16
#define MTOK (BB*TT)
#define NQ 4096            // q|k|v|g concat width
#define NW (NQ+128)        // wcat rows incl. small-proj block
#define TC 32              // scan chunk length
#define NC (TT/TC)         // 64 chunks
#define BH (BB*HH)         // 64
#define ROWT (16*NQ)       // elements per 16-row blocked stripe

typedef __bf16 bf16x8 __attribute__((ext_vector_type(8)));
typedef float f32x4 __attribute__((ext_vector_type(4)));

__device__ __forceinline__ uint16_t f2bf(float f){
  uint32_t u = __float_as_uint(f);
  u += 0x7fffu + ((u >> 16) & 1u);
  return (uint16_t)(u >> 16);
}
__device__ __forceinline__ float bf2f(uint32_t h){ return __uint_as_float(h << 16); }
// sigmoid via fast exp + raw v_rcp_f32 (1 ulp) -- avoids precise-div expansion
__device__ __forceinline__ float sigm(float z){
  return __builtin_amdgcn_rcpf(1.f + __expf(-z));
}

__device__ __forceinline__ void gll16(const uint16_t* src, uint16_t* dst){
  __builtin_amdgcn_global_load_lds(
      (const __attribute__((address_space(1))) void*)src,
      (__attribute__((address_space(3))) void*)dst, 16, 0, 0);
}
// extract bf16 element e (static) from a uint4 (8 bf16)
__device__ __forceinline__ float bfel(const uint4& v, int e){
  uint32_t wrd = ((e>>1)==0) ? v.x : ((e>>1)==1) ? v.y : ((e>>1)==2) ? v.z : v.w;
  return bf2f((e&1) ? (wrd >> 16) : (wrd & 0xffffu));
}

// ---------------- prep: pure casts ----------------
// blocks [0,5120): Wq|Wk|Wv|Wg -> wcat rows 0..4095, Wo -> wob  (1 float4/thr)
// blocks [5120,9216): x -> xb  (2 float4/thr)
// blocks [9216,9344): Wb|Wfd|Wsd|zeros -> wcat rows 4096..4223  (4 elems/thr)
__global__ __launch_bounds__(256) void prep_kernel(
    const float* __restrict__ x,
    const float* __restrict__ Wq, const float* __restrict__ Wk,
    const float* __restrict__ Wv, const float* __restrict__ Wg,
    const float* __restrict__ Wo,
    const float* __restrict__ Wb, const float* __restrict__ Wfd,
    const float* __restrict__ Wsd,
    uint16_t* __restrict__ wcat, uint16_t* __restrict__ wob,
    uint16_t* __restrict__ xb)
{
  const int bx = blockIdx.x;
  if (bx < 5120){
    int i = bx * 256 + threadIdx.x;      // float4 index; 262144 per weight
    int wsel = i >> 18;
    int loc = i & 262143;
    const float* src = (wsel == 0) ? Wq : (wsel == 1) ? Wk : (wsel == 2) ? Wv : (wsel == 3) ? Wg : Wo;
    uint16_t* dst = (wsel < 4) ? (wcat + (size_t)wsel * DD * DD) : wob;
    float4 v = ((const float4*)src)[loc];
    ushort4 o;
    o.x = f2bf(v.x); o.y = f2bf(v.y); o.z = f2bf(v.z); o.w = f2bf(v.w);
    ((ushort4*)dst)[loc] = o;
  } else if (bx < 9216){
    int base = (bx - 5120) * 512 + threadIdx.x;
    #pragma unroll
    for (int rep = 0; rep < 2; rep++){
      int loc = base + rep * 256;
      float4 v = ((const float4*)x)[loc];
      ushort4 o;
      o.x = f2bf(v.x); o.y = f2bf(v.y); o.z = f2bf(v.z); o.w = f2bf(v.w);
      ((ushort4*)xb)[loc] = o;
    }
  } else {
    int u = (bx - 9216) * 256 + threadIdx.x;   // 4-elem unit; 256 units/row
    int row = u >> 8;
    int cidx = (u & 255) * 4;
    ushort4 o = {0, 0, 0, 0};
    if (row < 48){
      const float* src = (row < 16) ? (Wb + (size_t)row * DD)
                       : (row < 32) ? (Wfd + (size_t)(row - 16) * DD)
                                    : (Wsd + (size_t)(row - 32) * DD);
      float4 v = *(const float4*)(src + cidx);
      o.x = f2bf(v.x); o.y = f2bf(v.y); o.z = f2bf(v.z); o.w = f2bf(v.w);
    }
    *(ushort4*)(wcat + (size_t)(NQ + row) * DD + cidx) = o;
  }
}

// =============== 128x128 GEMM, BK=64, m97 2-barrier structure (R8-exact config) ===============
// X:[M][K], W:[N][K] bf16 row-major. 256 thr = 4 waves (2x2), 64x64 per wave.
// 2D grid (x = n-tile, y = m-tile); x-width a multiple of 8 keeps XCD alignment.
// LDS 2x16KB single-buffered. Per-8-row XOR swizzle on 16B chunks:
// LDS chunk p holds logical (row=p>>3, quarter=(p&7)^(row&7)); inverse applied
// to the global source of global_load_lds (rule #21) -> 0 bank conflicts.
// MODE 0: qkvg blocked bf16 out (silu n0<3072, else sigmoid).
// MODE 1: plain f32 row-major out, no activation.
// MODE 2: small-proj (grid x=1, W = wcat rows 4096..): sigm(v+bias) -> sc f32 [3][B][H][T].
template<int MODE>
__global__ __launch_bounds__(256) void gemm128(
    const uint16_t* __restrict__ X, const uint16_t* __restrict__ W,
    uint16_t* __restrict__ Y, float* __restrict__ Yf,
    const float* __restrict__ bfd, const float* __restrict__ bsd,
    float* __restrict__ scp, int N, int K)
{
  __shared__ __align__(16) uint16_t lA[128 * 64];
  __shared__ __align__(16) uint16_t lB[128 * 64];
  const int tid = threadIdx.x;
  const int m0 = blockIdx.y * 128, n0 = blockIdx.x * 128;
  const int l = tid & 63, w = tid >> 6;
  const int wr = w >> 1, wc = w & 1;
  const int g = l >> 4, r16 = l & 15;

  // staging: chunk p = n*256 + tid; row = p>>3, logical quarter = (p&7)^(row&7)
  const uint16_t* srcA[4];
  const uint16_t* srcB[4];
  uint16_t* dstA[4];
  uint16_t* dstB[4];
  #pragma unroll
  for (int n = 0; n < 4; n++){
    int p = n * 256 + tid;
    int row = p >> 3;
    int cq = (p & 7) ^ (row & 7);
    srcA[n] = X + (size_t)(m0 + row) * K + cq * 8;
    srcB[n] = W + (size_t)(n0 + row) * K + cq * 8;
    int basechunk = n * 256 + (tid & ~63);     // wave-uniform
    dstA[n] = lA + basechunk * 8;
    dstB[n] = lB + basechunk * 8;
  }

  // frag read offsets (u16 idx): row*64 + ((ks*4+g)^(row&7))*8
  int roA[4][2], roB[4][2];
  #pragma unroll
  for (int i = 0; i < 4; i++)
    #pragma unroll
    for (int ks = 0; ks < 2; ks++){
      roA[i][ks] = (wr * 64 + i * 16 + r16) * 64 + ((ks * 4 + g) ^ (r16 & 7)) * 8;
      roB[i][ks] = (wc * 64 + i * 16 + r16) * 64 + ((ks * 4 + g) ^ (r16 & 7)) * 8;
    }

  f32x4 acc[4][4];
  #pragma unroll
  for (int i = 0; i < 4; i++)
    #pragma unroll
    for (int j = 0; j < 4; j++) acc[i][j] = (f32x4){0.f, 0.f, 0.f, 0.f};

  for (int kt = 0; kt < K; kt += 64){
    __syncthreads();                    // WAR: prior tile reads done
    #pragma unroll
    for (int n = 0; n < 4; n++){
      gll16(srcA[n] + kt, dstA[n]);
      gll16(srcB[n] + kt, dstB[n]);
    }
    __syncthreads();                    // compiler drains vmcnt(0) before barrier

    #pragma unroll
    for (int ks = 0; ks < 2; ks++){
      bf16x8 af[4], bw[4];
      #pragma unroll
      for (int mi = 0; mi < 4; mi++) af[mi] = *(const bf16x8*)(lA + roA[mi][ks]);
      #pragma unroll
      for (int ni = 0; ni < 4; ni++) bw[ni] = *(const bf16x8*)(lB + roB[ni][ks]);
      #pragma unroll
      for (int mi = 0; mi < 4; mi++)
        #pragma unroll
        for (int ni = 0; ni < 4; ni++)
          acc[mi][ni] = __builtin_amdgcn_mfma_f32_16x16x32_bf16(af[mi], bw[ni], acc[mi][ni], 0, 0, 0);
    }
  }

  // C/D layout: col=lane&15, row=(lane>>4)*4+reg  [m89-verified]
  if (MODE == 0){
    const bool dosig = (n0 >= 3 * DD);
    #pragma unroll
    for (int mi = 0; mi < 4; mi++){
      const int R0 = m0 + wr * 64 + mi * 16;
      const size_t rbase = (size_t)(R0 >> 4) * ROWT;
      #pragma unroll
      for (int ni = 0; ni < 4; ni++){
        const int C0 = n0 + wc * 64 + ni * 16;
        f32x4 v = acc[mi][ni];
        float o[4];
        #pragma unroll
        for (int r = 0; r < 4; r++){
          float xx = v[r];
          o[r] = dosig ? sigm(xx) : xx * sigm(xx);
        }
        uint2 pk;
        pk.x = (uint32_t)f2bf(o[0]) | ((uint32_t)f2bf(o[1]) << 16);
        pk.y = (uint32_t)f2bf(o[2]) | ((uint32_t)f2bf(o[3]) << 16);
        size_t off = rbase + (size_t)(C0 >> 4) * 256 + (size_t)r16 * 16 + g * 4;
        *(uint2*)(Y + off) = pk;
      }
    }
  } else if (MODE == 1){
    #pragma unroll
    for (int mi = 0; mi < 4; mi++){
      #pragma unroll
      for (int ni = 0; ni < 4; ni++){
        int rg = m0 + wr * 64 + mi * 16 + g * 4;
        int cg = n0 + wc * 64 + ni * 16 + r16;
        #pragma unroll
        for (int r = 0; r < 4; r++)
          Yf[(size_t)(rg + r) * N + cg] = acc[mi][ni][r];
      }
    }
  } else {
    // small-proj: cols 0..47 -> sc[grp][b][h][t] (f32), cols 48..127 discarded
    #pragma unroll
    for (int ni = 0; ni < 4; ni++){
      const int cc0 = wc * 64 + ni * 16;          // col block within tile
      const int grp = cc0 >> 4;
      if (grp < 3){
        const int h = r16;
        const float bias = (grp == 0) ? 0.f : (grp == 1) ? bfd[h] : bsd[h];
        #pragma unroll
        for (int mi = 0; mi < 4; mi++){
          const int R0 = m0 + wr * 64 + mi * 16 + g * 4;  // token rows R0..R0+3
          const int b = R0 >> 11, t = R0 & (TT - 1);
          f32x4 v = acc[mi][ni];
          float4 o;
          o.x = sigm(v[0] + bias);
          o.y = sigm(v[1] + bias);
          o.z = sigm(v[2] + bias);
          o.w = sigm(v[3] + bias);
          *(float4*)(scp + (((size_t)grp * BB + b) * HH + h) * TT + t) = o;
        }
      }
    }
  }
}

// ---------------- chunked scan over blocked qkvg ----------------
// blocked elem(R,C) = (R>>4)*ROWT + (C>>4)*256 + (C&15)*16 + (R&15)
// step: [sf,ss]' = M_t [sf,ss] + 1.05*u_t*[1,1],  M_t = [[f,.05s],[.05f,s]]

// Pass A: per (chunk j, bh): zero-entry local end state L + chunk 2x2 matrix P
__global__ __launch_bounds__(64) void scan_partA(
    const uint16_t* __restrict__ qkvg, const float* __restrict__ sc,
    float* __restrict__ Lst, float4* __restrict__ Pm)
{
  int j = blockIdx.x, bh = blockIdx.y;
  int b = bh >> 4, h = bh & 15;
  int c = threadIdx.x;
  const int ci = c & 15;
  const size_t tc_k = (size_t)((DD     + h * 64 + c) >> 4) * 256 + ci * 16;
  const size_t tc_v = (size_t)((2 * DD + h * 64 + c) >> 4) * 256 + ci * 16;
  const float* bet = sc + ((size_t)(0 * BB + b) * HH + h) * TT + j * TC;
  const float* fdp = sc + ((size_t)(1 * BB + b) * HH + h) * TT + j * TC;
  const float* sdp = sc + ((size_t)(2 * BB + b) * HH + h) * TT + j * TC;

  float sf = 0.f, ss = 0.f;
  float p00 = 1.f, p01 = 0.f, p10 = 0.f, p11 = 1.f;
  #pragma unroll
  for (int t16 = 0; t16 < 2; ++t16){
    int R0 = b * TT + j * TC + t16 * 16;
    size_t tb = (size_t)(R0 >> 4) * ROWT;
    uint4 kl = *(const uint4*)(qkvg + tb + tc_k);
    uint4 kh = *(const uint4*)(qkvg + tb + tc_k + 8);
    uint4 vl = *(const uint4*)(qkvg + tb + tc_v);
    uint4 vh = *(const uint4*)(qkvg + tb + tc_v + 8);
    const float* bt = bet + t16 * 16;
    const float* ft = fdp + t16 * 16;
    const float* st = sdp + t16 * 16;
    #pragma unroll
    for (int u = 0; u < 16; ++u){
      float kv = (u < 8) ? bfel(kl, u) : bfel(kh, u - 8);
      float vv = (u < 8) ? bfel(vl, u) : bfel(vh, u - 8);
      float btv = bt[u], f = ft[u], s = st[u];
      float uu = 1.05f * btv * kv * vv;
      float bq = 0.05f * s, cq = 0.05f * f;
      float nf = f * sf + bq * ss + uu;
      float ns = cq * sf + s * ss + uu;
      sf = nf; ss = ns;
      float q00 = f * p00 + bq * p10, q01 = f * p01 + bq * p11;
      float q10 = cq * p00 + s * p10, q11 = cq * p01 + s * p11;
      p00 = q00; p01 = q01; p10 = q10; p11 = q11;
    }
  }
  size_t base = ((size_t)bh * NC + j) * 2;
  Lst[(base + 0) * 64 + c] = sf;
  Lst[(base + 1) * 64 + c] = ss;
  if (c == 0) Pm[(size_t)bh * NC + j] = make_float4(p00, p01, p10, p11);
}

// Pass C (with folded lookback): compute entry state E_j from Lst/Pm (all
// written by partA, complete at kernel boundary -- deterministic, no atomics),
// then replay chunk and write og row-major via LDS micro-transpose.
__global__ __launch_bounds__(64) void scan_partC(
    const uint16_t* __restrict__ qkvg, const float* __restrict__ sc,
    const float* __restrict__ Lst, const float4* __restrict__ Pm,
    uint16_t* __restrict__ og)
{
  __shared__ uint16_t ot[16 * 64];
  int j = blockIdx.x, bh = blockIdx.y;
  int b = bh >> 4, h = bh & 15;
  int c = threadIdx.x;
  const int ci = c & 15;

  // forward lookback: E = P_i * E + L_i for i = 0..j-1
  float sf = 0.f, ss = 0.f;
  for (int i = 0; i < j; ++i){
    size_t pbase = ((size_t)bh * NC + i) * 2;
    float lf = Lst[(pbase + 0) * 64 + c];
    float ls = Lst[(pbase + 1) * 64 + c];
    float4 P = Pm[(size_t)bh * NC + i];
    float nf = P.x * sf + P.y * ss + lf;
    float ns = P.z * sf + P.w * ss + ls;
    sf = nf; ss = ns;
  }

  const size_t tc_q = (size_t)((         h * 64 + c) >> 4) * 256 + ci * 16;
  const size_t tc_k = (size_t)((DD     + h * 64 + c) >> 4) * 256 + ci * 16;
  const size_t tc_v = (size_t)((2 * DD + h * 64 + c) >> 4) * 256 + ci * 16;
  const size_t tc_g = (size_t)((3 * DD + h * 64 + c) >> 4) * 256 + ci * 16;
  const float* bet = sc + ((size_t)(0 * BB + b) * HH + h) * TT + j * TC;
  const float* fdp = sc + ((size_t)(1 * BB + b) * HH + h) * TT + j * TC;
  const float* sdp = sc + ((size_t)(2 * BB + b) * HH + h) * TT + j * TC;

  #pragma unroll
  for (int t16 = 0; t16 < 2; ++t16){
    int R0 = b * TT + j * TC + t16 * 16;
    size_t tb = (size_t)(R0 >> 4) * ROWT;
    uint4 ql = *(const uint4*)(qkvg + tb + tc_q);
    uint4 qh = *(const uint4*)(qkvg + tb + tc_q + 8);
    uint4 kl = *(const uint4*)(qkvg + tb + tc_k);
    uint4 kh = *(const uint4*)(qkvg + tb + tc_k + 8);
    uint4 vl = *(const uint4*)(qkvg + tb + tc_v);
    uint4 vh = *(const uint4*)(qkvg + tb + tc_v + 8);
    uint4 gl = *(const uint4*)(qkvg + tb + tc_g);
    uint4 gh = *(const uint4*)(qkvg + tb + tc_g + 8);
    const float* bt = bet + t16 * 16;
    const float* ft = fdp + t16 * 16;
    const float* st = sdp + t16 * 16;
    #pragma unroll
    for (int u = 0; u < 16; ++u){
      float qv = (u < 8) ? bfel(ql, u) : bfel(qh, u - 8);
      float kv = (u < 8) ? bfel(kl, u) : bfel(kh, u - 8);
      float vv = (u < 8) ? bfel(vl, u) : bfel(vh, u - 8);
      float gv = (u < 8) ? bfel(gl, u) : bfel(gh, u - 8);
      float btv = bt[u], f = ft[u], s = st[u];
      sf *= f; ss *= s;
      float o = 0.5f * qv * (sf + ss);
      float uu = btv * kv * vv;
      sf += uu; ss += uu;
      float nf = sf + 0.05f * ss, ns = ss + 0.05f * sf;
      sf = nf; ss = ns;
      ot[u * 64 + c] = f2bf(o * gv);
    }
    __syncthreads();
    {
      int u0 = c >> 3, c8 = c & 7;
      uint4 d0 = *(const uint4*)&ot[u0 * 64 + c8 * 8];
      uint4 d1 = *(const uint4*)&ot[(u0 + 8) * 64 + c8 * 8];
      uint16_t* ob = og + (size_t)R0 * DD + h * 64 + c8 * 8;
      *(uint4*)(ob + (size_t)u0 * DD) = d0;
      *(uint4*)(ob + (size_t)(u0 + 8) * DD) = d1;
    }
    __syncthreads();
  }
}

extern "C" void kernel_launch(void* const* d_in, const int* in_sizes, int n_in,
                              void* d_out, int out_size, void* d_ws, size_t ws_size,
                              hipStream_t stream)
{
  const float* x   = (const float*)d_in[0];
  const float* Wq  = (const float*)d_in[1];
  const float* Wk  = (const float*)d_in[2];
  const float* Wv  = (const float*)d_in[3];
  const float* Wo  = (const float*)d_in[4];
  const float* Wb  = (const float*)d_in[5];
  const float* Wfd = (const float*)d_in[6];
  const float* bfd = (const float*)d_in[7];
  const float* Wsd = (const float*)d_in[8];
  const float* bsd = (const float*)d_in[9];
  const float* Wg  = (const float*)d_in[10];
  float* out = (float*)d_out;

  char* ws = (char*)d_ws;
  size_t off = 0;
  auto alloc = [&](size_t bytes) -> void* {
    void* p = ws + off;
    off += (bytes + 255) & ~(size_t)255;
    return p;
  };

  uint16_t* xb   = (uint16_t*)alloc((size_t)MTOK * DD * 2);   // doubles as ogb later
  uint16_t* wcat = (uint16_t*)alloc((size_t)NW * DD * 2);     // Wq|Wk|Wv|Wg|small(128)
  uint16_t* wob  = (uint16_t*)alloc((size_t)DD * DD * 2);
  uint16_t* qkvg = (uint16_t*)alloc((size_t)MTOK * NQ * 2);   // blocked layout
  float*    sc   = (float*)alloc((size_t)3 * BB * HH * TT * 4);
  float*    Lst  = (float*)alloc((size_t)BH * NC * 2 * 64 * 4);
  float4*   Pm   = (float4*)alloc((size_t)BH * NC * 16);
  uint16_t* ogb  = xb;

  // prep: all casts (weights, x, small-proj weight block) in one dispatch
  prep_kernel<<<9344, 256, 0, stream>>>(
      x, Wq, Wk, Wv, Wg, Wo, Wb, Wfd, Wsd, wcat, wob, xb);

  // fused q|k|v|g GEMM: [8192,1024] @ [4096,1024]^T -> blocked bf16 (R8-exact 2D grid)
  dim3 gq(NQ / 128, MTOK / 128);
  gemm128<0><<<gq, 256, 0, stream>>>(xb, wcat, qkvg, nullptr, bfd, bsd, nullptr, NQ, DD);

  // small projections: [8192,1024] @ [128,1024]^T -> sc (f32), tiny MFMA GEMM
  dim3 gp(1, MTOK / 128);
  gemm128<2><<<gp, 256, 0, stream>>>(xb, wcat + (size_t)NQ * DD, nullptr, nullptr,
                                     bfd, bsd, sc, NQ, DD);

  // chunked scan: partA (local) then partC (lookback + replay)
  dim3 gs(NC, BH);
  scan_partA<<<gs, 64, 0, stream>>>(qkvg, sc, Lst, Pm);
  scan_partC<<<gs, 64, 0, stream>>>(qkvg, sc, Lst, Pm, ogb);

  // out = (o*g) @ Wo^T, fp32 row-major out (2D grid, 8%8==0 aligned)
  dim3 go(DD / 128, MTOK / 128);
  gemm128<1><<<go, 256, 0, stream>>>(ogb, wob, nullptr, out, bfd, bsd, nullptr, DD, DD);
}